// Round 2
// baseline (3332.217 us; speedup 1.0000x reference)
//
#include <hip/hip_runtime.h>

static constexpr int GRAPHS = 256;

__device__ __forceinline__ float lrelu(float v) { return fmaxf(v, 0.2f * v); }

// ---------------- utility ----------------
__global__ void zero_f32_kernel(float* __restrict__ p, int n) {
  int i = blockIdx.x * blockDim.x + threadIdx.x;
  if (i < n) p[i] = 0.0f;
}

// ---------------- CSR build (target-major adjacency incl. self loops) ----------------
__global__ void init_counts_kernel(int* __restrict__ cnt, int n) {
  int i = blockIdx.x * blockDim.x + threadIdx.x;
  if (i < n) cnt[i] = 1;  // self loop
}

__global__ void count_edges_kernel(const int* __restrict__ ei, int* __restrict__ cnt, int E) {
  int e = blockIdx.x * blockDim.x + threadIdx.x;
  if (e < E) atomicAdd(&cnt[ei[E + e]], 1);  // col = target
}

__global__ void scan_kernel(const int* __restrict__ counts, int* __restrict__ rowptr, int n) {
  __shared__ int sh[1024];
  int t = threadIdx.x;
  int chunk = (n + 1023) >> 10;
  int start = t * chunk;
  int end = min(start + chunk, n);
  int sum = 0;
  for (int i = start; i < end; ++i) sum += counts[i];
  sh[t] = sum;
  __syncthreads();
  for (int off = 1; off < 1024; off <<= 1) {
    int v = (t >= off) ? sh[t - off] : 0;
    __syncthreads();
    sh[t] += v;
    __syncthreads();
  }
  int run = sh[t] - sum;  // exclusive prefix
  for (int i = start; i < end; ++i) { rowptr[i] = run; run += counts[i]; }
  if (t == 1023) rowptr[n] = sh[1023];
}

__global__ void finalize_csr_kernel(const int* __restrict__ rowptr, float* __restrict__ dis,
                                    int* __restrict__ cursor, int* __restrict__ csr, int n) {
  int i = blockIdx.x * blockDim.x + threadIdx.x;
  if (i >= n) return;
  int s = rowptr[i], e = rowptr[i + 1];
  dis[i] = rsqrtf((float)(e - s));  // deg includes self loop, >= 1
  csr[s] = i;                       // self loop in slot 0
  cursor[i] = s + 1;
}

__global__ void fill_edges_kernel(const int* __restrict__ ei, int* __restrict__ cursor,
                                  int* __restrict__ csr, int E) {
  int e = blockIdx.x * blockDim.x + threadIdx.x;
  if (e >= E) return;
  int c = ei[E + e];  // target
  int pos = atomicAdd(&cursor[c], 1);
  csr[pos] = ei[e];  // source
}

// ---------------- dense GEMM: out[n,c] = sum_k x[n,k] * W[k,c] ----------------
// 2 nodes per thread (W-load reuse), float4 x loads, 8 independent accumulators.
template <int DIN, int DOUT>
__global__ void gemm_kernel(const float* __restrict__ x, const float* __restrict__ W,
                            float* __restrict__ out, int n_nodes) {
  int gid = blockIdx.x * blockDim.x + threadIdx.x;
  int pairs = (n_nodes + 1) >> 1;
  if (gid >= pairs * DOUT) return;
  int pair = gid / DOUT;
  int c = gid & (DOUT - 1);
  int n0 = pair * 2;
  bool has1 = (n0 + 1) < n_nodes;
  const float4* x0 = (const float4*)(x + (size_t)n0 * DIN);
  const float4* x1 = (const float4*)(x + (size_t)(has1 ? n0 + 1 : n0) * DIN);
  float a00 = 0.f, a01 = 0.f, a02 = 0.f, a03 = 0.f;
  float a10 = 0.f, a11 = 0.f, a12 = 0.f, a13 = 0.f;
#pragma unroll
  for (int k4 = 0; k4 < DIN / 4; ++k4) {
    float4 xa = x0[k4];
    float4 xb = x1[k4];
    const float* wc = W + (size_t)(k4 * 4) * DOUT + c;
    float w0 = wc[0], w1 = wc[DOUT], w2 = wc[2 * DOUT], w3 = wc[3 * DOUT];
    a00 = fmaf(xa.x, w0, a00);
    a01 = fmaf(xa.y, w1, a01);
    a02 = fmaf(xa.z, w2, a02);
    a03 = fmaf(xa.w, w3, a03);
    a10 = fmaf(xb.x, w0, a10);
    a11 = fmaf(xb.y, w1, a11);
    a12 = fmaf(xb.z, w2, a12);
    a13 = fmaf(xb.w, w3, a13);
  }
  out[(size_t)n0 * DOUT + c] = (a00 + a01) + (a02 + a03);
  if (has1) out[(size_t)(n0 + 1) * DOUT + c] = (a10 + a11) + (a12 + a13);
}

// ---------------- GCN aggregation: wave per node, atomic-free ----------------
template <int D>
__global__ void gcn_agg_kernel(const float* __restrict__ h, const int* __restrict__ rowptr,
                               const int* __restrict__ csr, const float* __restrict__ dis,
                               const float* __restrict__ bias, float* __restrict__ out, int n) {
  int wave = (blockIdx.x * blockDim.x + threadIdx.x) >> 6;
  int lane = threadIdx.x & 63;
  if (wave >= n) return;
  int s = rowptr[wave], e = rowptr[wave + 1];
  float acc0 = 0.f, acc1 = 0.f;
  for (int k = s; k < e; ++k) {
    int j = csr[k];
    float dj = dis[j];
    const float* hr = h + (size_t)j * D;
    acc0 = fmaf(dj, hr[lane], acc0);
    if (D == 128) acc1 = fmaf(dj, hr[lane + 64], acc1);
  }
  float di = dis[wave];
  out[(size_t)wave * D + lane] = fmaf(di, acc0, bias[lane]);
  if (D == 128) out[(size_t)wave * D + lane + 64] = fmaf(di, acc1, bias[lane + 64]);
}

// ---------------- BatchNorm ----------------
template <int D>
__global__ void bn_stats_kernel(const float* __restrict__ x, double* __restrict__ stats, int n) {
  int tid = threadIdx.x;
  int c = tid & (D - 1);
  const int rpb = 256 / D;
  float s1 = 0.f, s2 = 0.f;
  for (int r = blockIdx.x * rpb + tid / D; r < n; r += gridDim.x * rpb) {
    float v = x[(size_t)r * D + c];
    s1 += v;
    s2 = fmaf(v, v, s2);
  }
  atomicAdd(&stats[c], (double)s1);
  atomicAdd(&stats[D + c], (double)s2);
}

template <int D>
__global__ void bn_coef_kernel(const double* __restrict__ stats, const float* __restrict__ g,
                               const float* __restrict__ b, float* __restrict__ coef, int n) {
  int c = threadIdx.x;
  if (c >= D) return;
  double inv_n = 1.0 / (double)n;
  double mu = stats[c] * inv_n;
  double var = stats[D + c] * inv_n - mu * mu;  // biased variance (jnp.var)
  float A = (float)(1.0 / sqrt(var + 1e-5)) * g[c];
  coef[c] = A;
  coef[D + c] = b[c] - (float)mu * A;
}

template <int D, bool ACT>
__global__ void bn_apply_kernel(float* __restrict__ x, const float* __restrict__ coef, int total) {
  int gid = blockIdx.x * blockDim.x + threadIdx.x;
  if (gid >= total) return;
  int c = gid & (D - 1);
  float v = fmaf(x[gid], coef[c], coef[D + c]);
  if (ACT) v = lrelu(v);
  x[gid] = v;
}

// ---------------- GAT ----------------
template <int C>
__global__ void att_coef_kernel(const float* __restrict__ h2, const float* __restrict__ a_src,
                                const float* __restrict__ a_dst, float* __restrict__ asrc,
                                float* __restrict__ adst, int n) {
  int gid = blockIdx.x * blockDim.x + threadIdx.x;
  if (gid >= n * 4) return;
  int nd = gid >> 2, h = gid & 3;
  const float* hr = h2 + (size_t)nd * 4 * C + h * C;
  float s1 = 0.f, s2 = 0.f;
#pragma unroll
  for (int c = 0; c < C; ++c) {
    float v = hr[c];
    s1 = fmaf(v, a_src[h * C + c], s1);
    s2 = fmaf(v, a_dst[h * C + c], s2);
  }
  asrc[gid] = s1;
  adst[gid] = s2;
}

// wave per node; softmax over incoming edges is local (shift-invariant, no max pass).
template <int D, int C>
__global__ void gat_agg_kernel(const float* __restrict__ h2, const int* __restrict__ rowptr,
                               const int* __restrict__ csr, const float* __restrict__ asrc,
                               const float* __restrict__ adst, const float* __restrict__ bias,
                               const float* __restrict__ xres, float* __restrict__ out, int n) {
  int wave = (blockIdx.x * blockDim.x + threadIdx.x) >> 6;
  int lane = threadIdx.x & 63;
  if (wave >= n) return;
  const int h0 = lane / C;
  float ad0 = adst[wave * 4 + h0];
  float ad1 = 0.f;
  int h1 = 0;
  if (D == 128) {
    h1 = (lane + 64) / C;
    ad1 = adst[wave * 4 + h1];
  }
  float acc0 = 0.f, ss0 = 0.f, acc1 = 0.f, ss1 = 0.f;
  int s = rowptr[wave], e = rowptr[wave + 1];
  for (int k = s; k < e; ++k) {
    int j = csr[k];
    const float* hr = h2 + (size_t)j * D;
    float e0 = lrelu(asrc[j * 4 + h0] + ad0);
    float ex0 = __expf(e0);
    ss0 += ex0;
    acc0 = fmaf(ex0, hr[lane], acc0);
    if (D == 128) {
      float e1 = lrelu(asrc[j * 4 + h1] + ad1);
      float ex1 = __expf(e1);
      ss1 += ex1;
      acc1 = fmaf(ex1, hr[lane + 64], acc1);
    }
  }
  size_t base = (size_t)wave * D;
  float v0 = acc0 / ss0 + bias[lane] + xres[base + lane];
  out[base + lane] = lrelu(v0);
  if (D == 128) {
    float v1 = acc1 / ss1 + bias[lane + 64] + xres[base + lane + 64];
    out[base + lane + 64] = lrelu(v1);
  }
}

// ---------------- global mean pool (batch is sorted -> segmented reduce) ----------------
__global__ void graph_bounds_kernel(const int* __restrict__ batch, int* __restrict__ bounds,
                                    int n) {
  int g = threadIdx.x;  // one block of 256 threads; bounds[g] = lower_bound(batch, g)
  if (g >= GRAPHS) return;
  int lo = 0, hi = n;
  while (lo < hi) {
    int mid = (lo + hi) >> 1;
    if (batch[mid] < g)
      lo = mid + 1;
    else
      hi = mid;
  }
  bounds[g] = lo;
  if (g == 0) bounds[GRAPHS] = n;
}

// block (4 waves, lane = channel) per graph; no atomics, writes d_out directly.
__global__ void pool_kernel(const float* __restrict__ x, const int* __restrict__ bounds,
                            float* __restrict__ out) {
  __shared__ float sh[4][64];
  int g = blockIdx.x;
  int lane = threadIdx.x & 63, w = threadIdx.x >> 6;
  int s = bounds[g], e = bounds[g + 1];
  float acc = 0.f;
  for (int r = s + w; r < e; r += 4) acc += x[(size_t)r * 64 + lane];
  sh[w][lane] = acc;
  __syncthreads();
  if (w == 0) {
    float t = sh[0][lane] + sh[1][lane] + sh[2][lane] + sh[3][lane];
    out[(g << 6) + lane] = t / fmaxf((float)(e - s), 1.0f);
  }
}

// ---------------- host ----------------
extern "C" void kernel_launch(void* const* d_in, const int* in_sizes, int n_in, void* d_out,
                              int out_size, void* d_ws, size_t ws_size, hipStream_t stream) {
  const float* x_in = (const float*)d_in[0];
  const int* ei = (const int*)d_in[1];
  const int* batch = (const int*)d_in[2];
  const float* gcn_w[4] = {(const float*)d_in[3], (const float*)d_in[7], (const float*)d_in[11],
                           (const float*)d_in[15]};
  const float* gcn_b[4] = {(const float*)d_in[4], (const float*)d_in[8], (const float*)d_in[12],
                           (const float*)d_in[16]};
  const float* bn_g[4] = {(const float*)d_in[5], (const float*)d_in[9], (const float*)d_in[13],
                          (const float*)d_in[17]};
  const float* bn_b[4] = {(const float*)d_in[6], (const float*)d_in[10], (const float*)d_in[14],
                          (const float*)d_in[18]};
  const float* gat_w0 = (const float*)d_in[19];
  const float* gat_as0 = (const float*)d_in[20];
  const float* gat_ad0 = (const float*)d_in[21];
  const float* gat_b0 = (const float*)d_in[22];
  const float* gat_w2 = (const float*)d_in[23];
  const float* gat_as2 = (const float*)d_in[24];
  const float* gat_ad2 = (const float*)d_in[25];
  const float* gat_b2 = (const float*)d_in[26];

  const int N = in_sizes[2];      // 100000
  const int E = in_sizes[1] / 2;  // 1600000

  // workspace carve, 256B-aligned slices
  char* wp = (char*)d_ws;
  auto alloc = [&](size_t bytes) -> void* {
    void* p = (void*)wp;
    wp += (bytes + 255) & ~(size_t)255;
    return p;
  };
  double* stats = (double*)alloc(256 * sizeof(double));
  float* coef = (float*)alloc(256 * sizeof(float));
  int* rowptr = (int*)alloc((size_t)(N + 1) * 4);
  int* cursor = (int*)alloc((size_t)N * 4);
  int* csr = (int*)alloc((size_t)(N + E) * 4);
  float* dis = (float*)alloc((size_t)N * 4);
  float* bufA = (float*)alloc((size_t)N * 128 * 4);
  float* bufB = (float*)alloc((size_t)N * 128 * 4);
  float* bufC = (float*)alloc((size_t)N * 128 * 4);
  float* attS = (float*)alloc((size_t)N * 4 * 4);
  float* attD = (float*)alloc((size_t)N * 4 * 4);
  int* bounds = (int*)alloc((size_t)(GRAPHS + 1) * 4);
  if ((size_t)(wp - (char*)d_ws) > ws_size) return;

  const int B = 256;
  auto cd = [](int a, int b) { return (a + b - 1) / b; };

  // --- CSR build ---
  init_counts_kernel<<<cd(N, B), B, 0, stream>>>(cursor, N);
  count_edges_kernel<<<cd(E, B), B, 0, stream>>>(ei, cursor, E);
  scan_kernel<<<1, 1024, 0, stream>>>(cursor, rowptr, N);
  finalize_csr_kernel<<<cd(N, B), B, 0, stream>>>(rowptr, dis, cursor, csr, N);
  fill_edges_kernel<<<cd(E, B), B, 0, stream>>>(ei, cursor, csr, E);
  graph_bounds_kernel<<<1, 256, 0, stream>>>(batch, bounds, N);

  auto bn = [&](float* buf, int D, const float* g, const float* b, bool act) {
    zero_f32_kernel<<<cd(512, B), B, 0, stream>>>((float*)stats, 512);
    if (D == 64) {
      bn_stats_kernel<64><<<256, 256, 0, stream>>>(buf, stats, N);
      bn_coef_kernel<64><<<1, 64, 0, stream>>>(stats, g, b, coef, N);
      int total = N * 64;
      if (act)
        bn_apply_kernel<64, true><<<cd(total, B), B, 0, stream>>>(buf, coef, total);
      else
        bn_apply_kernel<64, false><<<cd(total, B), B, 0, stream>>>(buf, coef, total);
    } else {
      bn_stats_kernel<128><<<256, 256, 0, stream>>>(buf, stats, N);
      bn_coef_kernel<128><<<1, 128, 0, stream>>>(stats, g, b, coef, N);
      int total = N * 128;
      if (act)
        bn_apply_kernel<128, true><<<cd(total, B), B, 0, stream>>>(buf, coef, total);
      else
        bn_apply_kernel<128, false><<<cd(total, B), B, 0, stream>>>(buf, coef, total);
    }
  };

  // ---- Layer 0: GCN 16->64, BN ----
  gemm_kernel<16, 64><<<cd(((N + 1) / 2) * 64, B), B, 0, stream>>>(x_in, gcn_w[0], bufB, N);
  gcn_agg_kernel<64><<<cd(N * 64, B), B, 0, stream>>>(bufB, rowptr, csr, dis, gcn_b[0], bufC, N);
  bn(bufC, 64, bn_g[0], bn_b[0], false);
  // GAT0 (D=64, C=16) + residual + lrelu -> bufA
  gemm_kernel<64, 64><<<cd(((N + 1) / 2) * 64, B), B, 0, stream>>>(bufC, gat_w0, bufB, N);
  att_coef_kernel<16><<<cd(N * 4, B), B, 0, stream>>>(bufB, gat_as0, gat_ad0, attS, attD, N);
  gat_agg_kernel<64, 16><<<cd(N * 64, B), B, 0, stream>>>(bufB, rowptr, csr, attS, attD, gat_b0,
                                                          bufC, bufA, N);

  // ---- Layer 1: GCN 64->128, BN + lrelu -> bufC ----
  gemm_kernel<64, 128><<<cd(((N + 1) / 2) * 128, B), B, 0, stream>>>(bufA, gcn_w[1], bufB, N);
  gcn_agg_kernel<128><<<cd(N * 64, B), B, 0, stream>>>(bufB, rowptr, csr, dis, gcn_b[1], bufC, N);
  bn(bufC, 128, bn_g[1], bn_b[1], true);

  // ---- Layer 2: GCN 128->128, BN ----
  gemm_kernel<128, 128><<<cd(((N + 1) / 2) * 128, B), B, 0, stream>>>(bufC, gcn_w[2], bufB, N);
  gcn_agg_kernel<128><<<cd(N * 64, B), B, 0, stream>>>(bufB, rowptr, csr, dis, gcn_b[2], bufA, N);
  bn(bufA, 128, bn_g[2], bn_b[2], false);
  // GAT2 (D=128, C=32) + residual + lrelu -> bufC
  gemm_kernel<128, 128><<<cd(((N + 1) / 2) * 128, B), B, 0, stream>>>(bufA, gat_w2, bufB, N);
  att_coef_kernel<32><<<cd(N * 4, B), B, 0, stream>>>(bufB, gat_as2, gat_ad2, attS, attD, N);
  gat_agg_kernel<128, 32><<<cd(N * 64, B), B, 0, stream>>>(bufB, rowptr, csr, attS, attD, gat_b2,
                                                           bufA, bufC, N);

  // ---- Layer 3: GCN 128->64, BN (no act) -> bufA ----
  gemm_kernel<128, 64><<<cd(((N + 1) / 2) * 64, B), B, 0, stream>>>(bufC, gcn_w[3], bufB, N);
  gcn_agg_kernel<64><<<cd(N * 64, B), B, 0, stream>>>(bufB, rowptr, csr, dis, gcn_b[3], bufA, N);
  bn(bufA, 64, bn_g[3], bn_b[3], false);

  // ---- global mean pool (no atomics) ----
  pool_kernel<<<GRAPHS, 256, 0, stream>>>(bufA, bounds, (float*)d_out);
}

// Round 3
// 1716.943 us; speedup vs baseline: 1.9408x; 1.9408x over previous
//
#include <hip/hip_runtime.h>

static constexpr int GRAPHS = 256;

__device__ __forceinline__ float lrelu(float v) { return fmaxf(v, 0.2f * v); }

// ---------------- utility ----------------
__global__ void zero_f32_kernel(float* __restrict__ p, int n) {
  int i = blockIdx.x * blockDim.x + threadIdx.x;
  if (i < n) p[i] = 0.0f;
}

// ---------------- CSR build (target-major adjacency incl. self loops) ----------------
__global__ void init_counts_kernel(int* __restrict__ cnt, int n) {
  int i = blockIdx.x * blockDim.x + threadIdx.x;
  if (i < n) cnt[i] = 1;  // self loop
}

__global__ void count_edges_kernel(const int* __restrict__ ei, int* __restrict__ cnt, int E) {
  int e = blockIdx.x * blockDim.x + threadIdx.x;
  if (e < E) atomicAdd(&cnt[ei[E + e]], 1);  // col = target
}

__global__ void scan_kernel(const int* __restrict__ counts, int* __restrict__ rowptr, int n) {
  __shared__ int sh[1024];
  int t = threadIdx.x;
  int chunk = (n + 1023) >> 10;
  int start = t * chunk;
  int end = min(start + chunk, n);
  int sum = 0;
  for (int i = start; i < end; ++i) sum += counts[i];
  sh[t] = sum;
  __syncthreads();
  for (int off = 1; off < 1024; off <<= 1) {
    int v = (t >= off) ? sh[t - off] : 0;
    __syncthreads();
    sh[t] += v;
    __syncthreads();
  }
  int run = sh[t] - sum;  // exclusive prefix
  for (int i = start; i < end; ++i) { rowptr[i] = run; run += counts[i]; }
  if (t == 1023) rowptr[n] = sh[1023];
}

__global__ void finalize_csr_kernel(const int* __restrict__ rowptr, float* __restrict__ dis,
                                    int* __restrict__ cursor, int* __restrict__ csr, int n) {
  int i = blockIdx.x * blockDim.x + threadIdx.x;
  if (i >= n) return;
  int s = rowptr[i], e = rowptr[i + 1];
  dis[i] = rsqrtf((float)(e - s));  // deg includes self loop, >= 1
  csr[s] = i;                       // self loop in slot 0
  cursor[i] = s + 1;
}

__global__ void fill_edges_kernel(const int* __restrict__ ei, int* __restrict__ cursor,
                                  int* __restrict__ csr, int E) {
  int e = blockIdx.x * blockDim.x + threadIdx.x;
  if (e >= E) return;
  int c = ei[E + e];  // target
  int pos = atomicAdd(&cursor[c], 1);
  csr[pos] = ei[e];  // source
}

// ---------------- LDS-tiled GEMM: out[n,c] = sum_k x[n,k] * W[k,c] (+ bias) ----------------
// Block stages NODES contiguous x rows in LDS (each global element fetched once),
// threads hold MT-node x 4-col register tiles. W float4 loads stay L1/L2-hot.
template <int K, int DOUT, int MT>
__global__ void gemm_tile_kernel(const float* __restrict__ x, const float* __restrict__ W,
                                 const float* __restrict__ bias, float* __restrict__ out,
                                 int n_nodes) {
  constexpr int COLG = DOUT / 4;    // threads across columns
  constexpr int ROWG = 256 / COLG;  // node groups
  constexpr int NODES = ROWG * MT;  // nodes per block
  __shared__ float xs[NODES * K];
  int tid = threadIdx.x;
  int node0 = blockIdx.x * NODES;
  int limit = min(NODES, n_nodes - node0);
  // stage x tile: contiguous region, perfectly coalesced
  const float4* src = (const float4*)(x + (size_t)node0 * K);
  int tile_f4 = (limit * K) >> 2;
  for (int i = tid; i < tile_f4; i += 256) ((float4*)xs)[i] = src[i];
  __syncthreads();
  int cg = tid % COLG, rg = tid / COLG;
  int c0 = cg * 4;
  float acc[MT][4];
#pragma unroll
  for (int m = 0; m < MT; ++m)
#pragma unroll
    for (int i = 0; i < 4; ++i) acc[m][i] = 0.f;

  for (int k4 = 0; k4 < K / 4; ++k4) {
    int k = k4 * 4;
    float4 w0 = *(const float4*)(W + (size_t)(k + 0) * DOUT + c0);
    float4 w1 = *(const float4*)(W + (size_t)(k + 1) * DOUT + c0);
    float4 w2 = *(const float4*)(W + (size_t)(k + 2) * DOUT + c0);
    float4 w3 = *(const float4*)(W + (size_t)(k + 3) * DOUT + c0);
#pragma unroll
    for (int m = 0; m < MT; ++m) {
      float4 xv = *(const float4*)(xs + (rg * MT + m) * K + k);
      acc[m][0] = fmaf(xv.x, w0.x, acc[m][0]);
      acc[m][1] = fmaf(xv.x, w0.y, acc[m][1]);
      acc[m][2] = fmaf(xv.x, w0.z, acc[m][2]);
      acc[m][3] = fmaf(xv.x, w0.w, acc[m][3]);
      acc[m][0] = fmaf(xv.y, w1.x, acc[m][0]);
      acc[m][1] = fmaf(xv.y, w1.y, acc[m][1]);
      acc[m][2] = fmaf(xv.y, w1.z, acc[m][2]);
      acc[m][3] = fmaf(xv.y, w1.w, acc[m][3]);
      acc[m][0] = fmaf(xv.z, w2.x, acc[m][0]);
      acc[m][1] = fmaf(xv.z, w2.y, acc[m][1]);
      acc[m][2] = fmaf(xv.z, w2.z, acc[m][2]);
      acc[m][3] = fmaf(xv.z, w2.w, acc[m][3]);
      acc[m][0] = fmaf(xv.w, w3.x, acc[m][0]);
      acc[m][1] = fmaf(xv.w, w3.y, acc[m][1]);
      acc[m][2] = fmaf(xv.w, w3.z, acc[m][2]);
      acc[m][3] = fmaf(xv.w, w3.w, acc[m][3]);
    }
  }
  float4 bv = make_float4(0.f, 0.f, 0.f, 0.f);
  if (bias) bv = *(const float4*)(bias + c0);
#pragma unroll
  for (int m = 0; m < MT; ++m) {
    int node = node0 + rg * MT + m;
    if (node < n_nodes) {
      float4 r;
      r.x = acc[m][0] + bv.x;
      r.y = acc[m][1] + bv.y;
      r.z = acc[m][2] + bv.z;
      r.w = acc[m][3] + bv.w;
      *(float4*)(out + (size_t)node * DOUT + c0) = r;
    }
  }
}

// ---------------- GCN aggregation (agg-only; GCN is linear so agg commutes with W) ----
// D=16: wave handles one node, 4 edges per iteration (lane = 16*q + c), xor-shuffle reduce.
__global__ void gcn_agg16_kernel(const float* __restrict__ h, const int* __restrict__ rowptr,
                                 const int* __restrict__ csr, const float* __restrict__ dis,
                                 float* __restrict__ out, int n) {
  int wave = (blockIdx.x * blockDim.x + threadIdx.x) >> 6;
  int lane = threadIdx.x & 63;
  if (wave >= n) return;
  int s = rowptr[wave], e = rowptr[wave + 1];
  int q = lane >> 4, c = lane & 15;
  float acc = 0.f;
  for (int k = s + q; k < e; k += 4) {
    int j = csr[k];
    acc = fmaf(dis[j], h[(size_t)j * 16 + c], acc);
  }
  acc += __shfl_xor(acc, 16, 64);
  acc += __shfl_xor(acc, 32, 64);
  if (lane < 16) out[(size_t)wave * 16 + lane] = dis[wave] * acc;
}

// D=64/128: wave per node, 2-edge unroll (independent fma/load chains). bias nullable.
template <int D>
__global__ void gcn_agg_kernel(const float* __restrict__ h, const int* __restrict__ rowptr,
                               const int* __restrict__ csr, const float* __restrict__ dis,
                               const float* __restrict__ bias, float* __restrict__ out, int n) {
  int wave = (blockIdx.x * blockDim.x + threadIdx.x) >> 6;
  int lane = threadIdx.x & 63;
  if (wave >= n) return;
  int s = rowptr[wave], e = rowptr[wave + 1];
  float accA0 = 0.f, accA1 = 0.f, accB0 = 0.f, accB1 = 0.f;
  int k = s;
  for (; k + 2 <= e; k += 2) {
    int j0 = csr[k], j1 = csr[k + 1];
    float d0 = dis[j0], d1 = dis[j1];
    const float* r0 = h + (size_t)j0 * D;
    const float* r1 = h + (size_t)j1 * D;
    accA0 = fmaf(d0, r0[lane], accA0);
    accB0 = fmaf(d1, r1[lane], accB0);
    if (D == 128) {
      accA1 = fmaf(d0, r0[lane + 64], accA1);
      accB1 = fmaf(d1, r1[lane + 64], accB1);
    }
  }
  if (k < e) {
    int j0 = csr[k];
    float d0 = dis[j0];
    const float* r0 = h + (size_t)j0 * D;
    accA0 = fmaf(d0, r0[lane], accA0);
    if (D == 128) accA1 = fmaf(d0, r0[lane + 64], accA1);
  }
  float di = dis[wave];
  float b0 = bias ? bias[lane] : 0.f;
  out[(size_t)wave * D + lane] = fmaf(di, accA0 + accB0, b0);
  if (D == 128) {
    float b1 = bias ? bias[lane + 64] : 0.f;
    out[(size_t)wave * D + lane + 64] = fmaf(di, accA1 + accB1, b1);
  }
}

// ---------------- BatchNorm ----------------
template <int D>
__global__ void bn_stats_kernel(const float* __restrict__ x, double* __restrict__ stats, int n) {
  int tid = threadIdx.x;
  int c = tid & (D - 1);
  const int rpb = 256 / D;
  float s1 = 0.f, s2 = 0.f;
  for (int r = blockIdx.x * rpb + tid / D; r < n; r += gridDim.x * rpb) {
    float v = x[(size_t)r * D + c];
    s1 += v;
    s2 = fmaf(v, v, s2);
  }
  atomicAdd(&stats[c], (double)s1);
  atomicAdd(&stats[D + c], (double)s2);
}

template <int D>
__global__ void bn_coef_kernel(const double* __restrict__ stats, const float* __restrict__ g,
                               const float* __restrict__ b, float* __restrict__ coef, int n) {
  int c = threadIdx.x;
  if (c >= D) return;
  double inv_n = 1.0 / (double)n;
  double mu = stats[c] * inv_n;
  double var = stats[D + c] * inv_n - mu * mu;  // biased variance (jnp.var)
  float A = (float)(1.0 / sqrt(var + 1e-5)) * g[c];
  coef[c] = A;
  coef[D + c] = b[c] - (float)mu * A;
}

template <int D, bool ACT>
__global__ void bn_apply_kernel(float* __restrict__ x, const float* __restrict__ coef, int total) {
  int gid = blockIdx.x * blockDim.x + threadIdx.x;
  if (gid >= total) return;
  int c = gid & (D - 1);
  float v = fmaf(x[gid], coef[c], coef[D + c]);
  if (ACT) v = lrelu(v);
  x[gid] = v;
}

// ---------------- GAT ----------------
template <int C>
__global__ void att_coef_kernel(const float* __restrict__ h2, const float* __restrict__ a_src,
                                const float* __restrict__ a_dst, float* __restrict__ asrc,
                                float* __restrict__ adst, int n) {
  int gid = blockIdx.x * blockDim.x + threadIdx.x;
  if (gid >= n * 4) return;
  int nd = gid >> 2, h = gid & 3;
  const float* hr = h2 + (size_t)nd * 4 * C + h * C;
  float s1 = 0.f, s2 = 0.f;
#pragma unroll
  for (int c = 0; c < C; ++c) {
    float v = hr[c];
    s1 = fmaf(v, a_src[h * C + c], s1);
    s2 = fmaf(v, a_dst[h * C + c], s2);
  }
  asrc[gid] = s1;
  adst[gid] = s2;
}

// wave per node; softmax over incoming edges is local (shift-invariant, no max pass).
template <int D, int C>
__global__ void gat_agg_kernel(const float* __restrict__ h2, const int* __restrict__ rowptr,
                               const int* __restrict__ csr, const float* __restrict__ asrc,
                               const float* __restrict__ adst, const float* __restrict__ bias,
                               const float* __restrict__ xres, float* __restrict__ out, int n) {
  int wave = (blockIdx.x * blockDim.x + threadIdx.x) >> 6;
  int lane = threadIdx.x & 63;
  if (wave >= n) return;
  const int h0 = lane / C;
  float ad0 = adst[wave * 4 + h0];
  float ad1 = 0.f;
  int h1 = 0;
  if (D == 128) {
    h1 = (lane + 64) / C;
    ad1 = adst[wave * 4 + h1];
  }
  float accA0 = 0.f, ssA0 = 0.f, accA1 = 0.f, ssA1 = 0.f;
  float accB0 = 0.f, ssB0 = 0.f, accB1 = 0.f, ssB1 = 0.f;
  int s = rowptr[wave], e = rowptr[wave + 1];
  int k = s;
  for (; k + 2 <= e; k += 2) {
    int j0 = csr[k], j1 = csr[k + 1];
    const float* r0 = h2 + (size_t)j0 * D;
    const float* r1 = h2 + (size_t)j1 * D;
    float exA0 = __expf(lrelu(asrc[j0 * 4 + h0] + ad0));
    float exB0 = __expf(lrelu(asrc[j1 * 4 + h0] + ad0));
    ssA0 += exA0;
    ssB0 += exB0;
    accA0 = fmaf(exA0, r0[lane], accA0);
    accB0 = fmaf(exB0, r1[lane], accB0);
    if (D == 128) {
      float exA1 = __expf(lrelu(asrc[j0 * 4 + h1] + ad1));
      float exB1 = __expf(lrelu(asrc[j1 * 4 + h1] + ad1));
      ssA1 += exA1;
      ssB1 += exB1;
      accA1 = fmaf(exA1, r0[lane + 64], accA1);
      accB1 = fmaf(exB1, r1[lane + 64], accB1);
    }
  }
  if (k < e) {
    int j0 = csr[k];
    const float* r0 = h2 + (size_t)j0 * D;
    float exA0 = __expf(lrelu(asrc[j0 * 4 + h0] + ad0));
    ssA0 += exA0;
    accA0 = fmaf(exA0, r0[lane], accA0);
    if (D == 128) {
      float exA1 = __expf(lrelu(asrc[j0 * 4 + h1] + ad1));
      ssA1 += exA1;
      accA1 = fmaf(exA1, r0[lane + 64], accA1);
    }
  }
  size_t base = (size_t)wave * D;
  float v0 = (accA0 + accB0) / (ssA0 + ssB0) + bias[lane] + xres[base + lane];
  out[base + lane] = lrelu(v0);
  if (D == 128) {
    float v1 = (accA1 + accB1) / (ssA1 + ssB1) + bias[lane + 64] + xres[base + lane + 64];
    out[base + lane + 64] = lrelu(v1);
  }
}

// ---------------- global mean pool (batch is sorted -> segmented reduce) ----------------
__global__ void graph_bounds_kernel(const int* __restrict__ batch, int* __restrict__ bounds,
                                    int n) {
  int g = threadIdx.x;
  if (g >= GRAPHS) return;
  int lo = 0, hi = n;
  while (lo < hi) {
    int mid = (lo + hi) >> 1;
    if (batch[mid] < g)
      lo = mid + 1;
    else
      hi = mid;
  }
  bounds[g] = lo;
  if (g == 0) bounds[GRAPHS] = n;
}

__global__ void pool_kernel(const float* __restrict__ x, const int* __restrict__ bounds,
                            float* __restrict__ out) {
  __shared__ float sh[4][64];
  int g = blockIdx.x;
  int lane = threadIdx.x & 63, w = threadIdx.x >> 6;
  int s = bounds[g], e = bounds[g + 1];
  float acc = 0.f;
  for (int r = s + w; r < e; r += 4) acc += x[(size_t)r * 64 + lane];
  sh[w][lane] = acc;
  __syncthreads();
  if (w == 0) {
    float t = sh[0][lane] + sh[1][lane] + sh[2][lane] + sh[3][lane];
    out[(g << 6) + lane] = t / fmaxf((float)(e - s), 1.0f);
  }
}

// ---------------- host ----------------
extern "C" void kernel_launch(void* const* d_in, const int* in_sizes, int n_in, void* d_out,
                              int out_size, void* d_ws, size_t ws_size, hipStream_t stream) {
  const float* x_in = (const float*)d_in[0];
  const int* ei = (const int*)d_in[1];
  const int* batch = (const int*)d_in[2];
  const float* gcn_w[4] = {(const float*)d_in[3], (const float*)d_in[7], (const float*)d_in[11],
                           (const float*)d_in[15]};
  const float* gcn_b[4] = {(const float*)d_in[4], (const float*)d_in[8], (const float*)d_in[12],
                           (const float*)d_in[16]};
  const float* bn_g[4] = {(const float*)d_in[5], (const float*)d_in[9], (const float*)d_in[13],
                          (const float*)d_in[17]};
  const float* bn_b[4] = {(const float*)d_in[6], (const float*)d_in[10], (const float*)d_in[14],
                          (const float*)d_in[18]};
  const float* gat_w0 = (const float*)d_in[19];
  const float* gat_as0 = (const float*)d_in[20];
  const float* gat_ad0 = (const float*)d_in[21];
  const float* gat_b0 = (const float*)d_in[22];
  const float* gat_w2 = (const float*)d_in[23];
  const float* gat_as2 = (const float*)d_in[24];
  const float* gat_ad2 = (const float*)d_in[25];
  const float* gat_b2 = (const float*)d_in[26];

  const int N = in_sizes[2];      // 100000
  const int E = in_sizes[1] / 2;  // 1600000

  char* wp = (char*)d_ws;
  auto alloc = [&](size_t bytes) -> void* {
    void* p = (void*)wp;
    wp += (bytes + 255) & ~(size_t)255;
    return p;
  };
  double* stats = (double*)alloc(256 * sizeof(double));
  float* coef = (float*)alloc(256 * sizeof(float));
  int* rowptr = (int*)alloc((size_t)(N + 1) * 4);
  int* cursor = (int*)alloc((size_t)N * 4);
  int* csr = (int*)alloc((size_t)(N + E) * 4);
  float* dis = (float*)alloc((size_t)N * 4);
  float* bufA = (float*)alloc((size_t)N * 128 * 4);
  float* bufB = (float*)alloc((size_t)N * 128 * 4);
  float* bufC = (float*)alloc((size_t)N * 128 * 4);
  float* attS = (float*)alloc((size_t)N * 4 * 4);
  float* attD = (float*)alloc((size_t)N * 4 * 4);
  int* bounds = (int*)alloc((size_t)(GRAPHS + 1) * 4);
  if ((size_t)(wp - (char*)d_ws) > ws_size) return;

  const int B = 256;
  auto cd = [](int a, int b) { return (a + b - 1) / b; };

  // --- CSR build ---
  init_counts_kernel<<<cd(N, B), B, 0, stream>>>(cursor, N);
  count_edges_kernel<<<cd(E, B), B, 0, stream>>>(ei, cursor, E);
  scan_kernel<<<1, 1024, 0, stream>>>(cursor, rowptr, N);
  finalize_csr_kernel<<<cd(N, B), B, 0, stream>>>(rowptr, dis, cursor, csr, N);
  fill_edges_kernel<<<cd(E, B), B, 0, stream>>>(ei, cursor, csr, E);
  graph_bounds_kernel<<<1, 256, 0, stream>>>(batch, bounds, N);

  auto bn = [&](float* buf, int D, const float* g, const float* b, bool act) {
    zero_f32_kernel<<<cd(512, B), B, 0, stream>>>((float*)stats, 512);
    if (D == 64) {
      bn_stats_kernel<64><<<256, 256, 0, stream>>>(buf, stats, N);
      bn_coef_kernel<64><<<1, 64, 0, stream>>>(stats, g, b, coef, N);
      int total = N * 64;
      if (act)
        bn_apply_kernel<64, true><<<cd(total, B), B, 0, stream>>>(buf, coef, total);
      else
        bn_apply_kernel<64, false><<<cd(total, B), B, 0, stream>>>(buf, coef, total);
    } else {
      bn_stats_kernel<128><<<256, 256, 0, stream>>>(buf, stats, N);
      bn_coef_kernel<128><<<1, 128, 0, stream>>>(stats, g, b, coef, N);
      int total = N * 128;
      if (act)
        bn_apply_kernel<128, true><<<cd(total, B), B, 0, stream>>>(buf, coef, total);
      else
        bn_apply_kernel<128, false><<<cd(total, B), B, 0, stream>>>(buf, coef, total);
    }
  };

  // ---- Layer 0: GCN 16->64 (aggregate at 16, then transform), BN ----
  gcn_agg16_kernel<<<cd(N * 64, B), B, 0, stream>>>(x_in, rowptr, csr, dis, bufB, N);
  gemm_tile_kernel<16, 64, 8><<<cd(N, 128), B, 0, stream>>>(bufB, gcn_w[0], gcn_b[0], bufC, N);
  bn(bufC, 64, bn_g[0], bn_b[0], false);
  // GAT0 (D=64, C=16) + residual + lrelu -> bufA
  gemm_tile_kernel<64, 64, 8><<<cd(N, 128), B, 0, stream>>>(bufC, gat_w0, nullptr, bufB, N);
  att_coef_kernel<16><<<cd(N * 4, B), B, 0, stream>>>(bufB, gat_as0, gat_ad0, attS, attD, N);
  gat_agg_kernel<64, 16><<<cd(N * 64, B), B, 0, stream>>>(bufB, rowptr, csr, attS, attD, gat_b0,
                                                          bufC, bufA, N);

  // ---- Layer 1: GCN 64->128 (aggregate at 64, then transform), BN + lrelu -> bufC ----
  gcn_agg_kernel<64><<<cd(N * 64, B), B, 0, stream>>>(bufA, rowptr, csr, dis, nullptr, bufB, N);
  gemm_tile_kernel<64, 128, 8><<<cd(N, 64), B, 0, stream>>>(bufB, gcn_w[1], gcn_b[1], bufC, N);
  bn(bufC, 128, bn_g[1], bn_b[1], true);

  // ---- Layer 2: GCN 128->128 (aggregate first), BN ----
  gcn_agg_kernel<128><<<cd(N * 64, B), B, 0, stream>>>(bufC, rowptr, csr, dis, nullptr, bufB, N);
  gemm_tile_kernel<128, 128, 8><<<cd(N, 64), B, 0, stream>>>(bufB, gcn_w[2], gcn_b[2], bufA, N);
  bn(bufA, 128, bn_g[2], bn_b[2], false);
  // GAT2 (D=128, C=32) + residual + lrelu -> bufC
  gemm_tile_kernel<128, 128, 8><<<cd(N, 64), B, 0, stream>>>(bufA, gat_w2, nullptr, bufB, N);
  att_coef_kernel<32><<<cd(N * 4, B), B, 0, stream>>>(bufB, gat_as2, gat_ad2, attS, attD, N);
  gat_agg_kernel<128, 32><<<cd(N * 64, B), B, 0, stream>>>(bufB, rowptr, csr, attS, attD, gat_b2,
                                                           bufA, bufC, N);

  // ---- Layer 3: GCN 128->64 (transform first, aggregate at 64 with bias), BN ----
  gemm_tile_kernel<128, 64, 4><<<cd(N, 64), B, 0, stream>>>(bufC, gcn_w[3], nullptr, bufB, N);
  gcn_agg_kernel<64><<<cd(N * 64, B), B, 0, stream>>>(bufB, rowptr, csr, dis, gcn_b[3], bufA, N);
  bn(bufA, 64, bn_g[3], bn_b[3], false);

  // ---- global mean pool ----
  pool_kernel<<<GRAPHS, 256, 0, stream>>>(bufA, bounds, (float*)d_out);
}

// Round 4
// 1494.048 us; speedup vs baseline: 2.2303x; 1.1492x over previous
//
#include <hip/hip_runtime.h>

static constexpr int GRAPHS = 256;
static constexpr int SCAN_CHUNK = 1024;  // elements per scan block

__device__ __forceinline__ float lrelu(float v) { return fmaxf(v, 0.2f * v); }

// ---------------- utility ----------------
__global__ void zero_f32_kernel(float* __restrict__ p, int n) {
  int i = blockIdx.x * blockDim.x + threadIdx.x;
  if (i < n) p[i] = 0.0f;
}

// ---------------- CSR build (target-major adjacency incl. self loops) ----------------
__global__ void init_counts_kernel(int* __restrict__ cnt, int n) {
  int i = blockIdx.x * blockDim.x + threadIdx.x;
  if (i < n) cnt[i] = 1;  // self loop
}

__global__ void count_edges_kernel(const int* __restrict__ ei, int* __restrict__ cnt, int E) {
  int e = blockIdx.x * blockDim.x + threadIdx.x;
  if (e < E) atomicAdd(&cnt[ei[E + e]], 1);  // col = target
}

// ---- 3-phase exclusive scan of counts[0..n) -> rowptr[0..n], rowptr[n]=total ----
__global__ void block_sum_kernel(const int* __restrict__ counts, int* __restrict__ partial,
                                 int n) {
  __shared__ int sh[256];
  int base = blockIdx.x * SCAN_CHUNK;
  int t = threadIdx.x;
  int lim = min(base + SCAN_CHUNK, n);
  int s = 0;
  for (int i = base + t; i < lim; i += 256) s += counts[i];
  sh[t] = s;
  __syncthreads();
  for (int off = 128; off > 0; off >>= 1) {
    if (t < off) sh[t] += sh[t + off];
    __syncthreads();
  }
  if (t == 0) partial[blockIdx.x] = sh[0];
}

__global__ void partial_scan_kernel(int* __restrict__ partial, int* __restrict__ rowptr,
                                    int nblocks, int n) {
  __shared__ int sh[256];
  int t = threadIdx.x;
  int v = (t < nblocks) ? partial[t] : 0;
  sh[t] = v;
  __syncthreads();
  for (int off = 1; off < 256; off <<= 1) {
    int u = (t >= off) ? sh[t - off] : 0;
    __syncthreads();
    sh[t] += u;
    __syncthreads();
  }
  if (t < nblocks) partial[t] = sh[t] - v;  // exclusive
  if (t == 255) rowptr[n] = sh[255];        // grand total
}

__global__ void chunk_scan_kernel(const int* __restrict__ counts, const int* __restrict__ partial,
                                  int* __restrict__ rowptr, int n) {
  __shared__ int sh[256];
  int base = blockIdx.x * SCAN_CHUNK;
  int t = threadIdx.x;
  int i0 = base + t * 4;
  int c0 = 0, c1 = 0, c2 = 0, c3 = 0;
  if (i0 + 3 < n) {
    int4 c = *(const int4*)(counts + i0);
    c0 = c.x;
    c1 = c.y;
    c2 = c.z;
    c3 = c.w;
  } else {
    if (i0 < n) c0 = counts[i0];
    if (i0 + 1 < n) c1 = counts[i0 + 1];
    if (i0 + 2 < n) c2 = counts[i0 + 2];
  }
  int tot = c0 + c1 + c2 + c3;
  sh[t] = tot;
  __syncthreads();
  for (int off = 1; off < 256; off <<= 1) {
    int u = (t >= off) ? sh[t - off] : 0;
    __syncthreads();
    sh[t] += u;
    __syncthreads();
  }
  int run = partial[blockIdx.x] + sh[t] - tot;  // exclusive prefix at i0
  if (i0 < n) { rowptr[i0] = run; run += c0; }
  if (i0 + 1 < n) { rowptr[i0 + 1] = run; run += c1; }
  if (i0 + 2 < n) { rowptr[i0 + 2] = run; run += c2; }
  if (i0 + 3 < n) { rowptr[i0 + 3] = run; }
}

__global__ void finalize_csr_kernel(const int* __restrict__ rowptr, float* __restrict__ dis,
                                    int* __restrict__ cursor, int* __restrict__ csr, int n) {
  int i = blockIdx.x * blockDim.x + threadIdx.x;
  if (i >= n) return;
  int s = rowptr[i], e = rowptr[i + 1];
  dis[i] = rsqrtf((float)(e - s));  // deg includes self loop, >= 1
  csr[s] = i;                       // self loop in slot 0
  cursor[i] = s + 1;
}

__global__ void fill_edges_kernel(const int* __restrict__ ei, int* __restrict__ cursor,
                                  int* __restrict__ csr, int E) {
  int e = blockIdx.x * blockDim.x + threadIdx.x;
  if (e >= E) return;
  int c = ei[E + e];  // target
  int pos = atomicAdd(&cursor[c], 1);
  csr[pos] = ei[e];  // source
}

// ---------------- LDS-tiled GEMM: out[n,c] = sum_k x[n,k] * W[k,c] (+ bias) ----------------
template <int K, int DOUT, int MT>
__global__ void gemm_tile_kernel(const float* __restrict__ x, const float* __restrict__ W,
                                 const float* __restrict__ bias, float* __restrict__ out,
                                 int n_nodes) {
  constexpr int COLG = DOUT / 4;    // threads across columns
  constexpr int ROWG = 256 / COLG;  // node groups
  constexpr int NODES = ROWG * MT;  // nodes per block
  __shared__ float xs[NODES * K];
  int tid = threadIdx.x;
  int node0 = blockIdx.x * NODES;
  int limit = min(NODES, n_nodes - node0);
  const float4* src = (const float4*)(x + (size_t)node0 * K);
  int tile_f4 = (limit * K) >> 2;
  for (int i = tid; i < tile_f4; i += 256) ((float4*)xs)[i] = src[i];
  __syncthreads();
  int cg = tid % COLG, rg = tid / COLG;
  int c0 = cg * 4;
  float acc[MT][4];
#pragma unroll
  for (int m = 0; m < MT; ++m)
#pragma unroll
    for (int i = 0; i < 4; ++i) acc[m][i] = 0.f;

  for (int k4 = 0; k4 < K / 4; ++k4) {
    int k = k4 * 4;
    float4 w0 = *(const float4*)(W + (size_t)(k + 0) * DOUT + c0);
    float4 w1 = *(const float4*)(W + (size_t)(k + 1) * DOUT + c0);
    float4 w2 = *(const float4*)(W + (size_t)(k + 2) * DOUT + c0);
    float4 w3 = *(const float4*)(W + (size_t)(k + 3) * DOUT + c0);
#pragma unroll
    for (int m = 0; m < MT; ++m) {
      float4 xv = *(const float4*)(xs + (rg * MT + m) * K + k);
      acc[m][0] = fmaf(xv.x, w0.x, acc[m][0]);
      acc[m][1] = fmaf(xv.x, w0.y, acc[m][1]);
      acc[m][2] = fmaf(xv.x, w0.z, acc[m][2]);
      acc[m][3] = fmaf(xv.x, w0.w, acc[m][3]);
      acc[m][0] = fmaf(xv.y, w1.x, acc[m][0]);
      acc[m][1] = fmaf(xv.y, w1.y, acc[m][1]);
      acc[m][2] = fmaf(xv.y, w1.z, acc[m][2]);
      acc[m][3] = fmaf(xv.y, w1.w, acc[m][3]);
      acc[m][0] = fmaf(xv.z, w2.x, acc[m][0]);
      acc[m][1] = fmaf(xv.z, w2.y, acc[m][1]);
      acc[m][2] = fmaf(xv.z, w2.z, acc[m][2]);
      acc[m][3] = fmaf(xv.z, w2.w, acc[m][3]);
      acc[m][0] = fmaf(xv.w, w3.x, acc[m][0]);
      acc[m][1] = fmaf(xv.w, w3.y, acc[m][1]);
      acc[m][2] = fmaf(xv.w, w3.z, acc[m][2]);
      acc[m][3] = fmaf(xv.w, w3.w, acc[m][3]);
    }
  }
  float4 bv = make_float4(0.f, 0.f, 0.f, 0.f);
  if (bias) bv = *(const float4*)(bias + c0);
#pragma unroll
  for (int m = 0; m < MT; ++m) {
    int node = node0 + rg * MT + m;
    if (node < n_nodes) {
      float4 r;
      r.x = acc[m][0] + bv.x;
      r.y = acc[m][1] + bv.y;
      r.z = acc[m][2] + bv.z;
      r.w = acc[m][3] + bv.w;
      *(float4*)(out + (size_t)node * DOUT + c0) = r;
    }
  }
}

// ---------------- GCN aggregation (agg-only; GCN is linear so agg commutes with W) ----
__global__ void gcn_agg16_kernel(const float* __restrict__ h, const int* __restrict__ rowptr,
                                 const int* __restrict__ csr, const float* __restrict__ dis,
                                 float* __restrict__ out, int n) {
  int wave = (blockIdx.x * blockDim.x + threadIdx.x) >> 6;
  int lane = threadIdx.x & 63;
  if (wave >= n) return;
  int s = rowptr[wave], e = rowptr[wave + 1];
  int q = lane >> 4, c = lane & 15;
  float acc = 0.f;
  for (int k = s + q; k < e; k += 4) {
    int j = csr[k];
    acc = fmaf(dis[j], h[(size_t)j * 16 + c], acc);
  }
  acc += __shfl_xor(acc, 16, 64);
  acc += __shfl_xor(acc, 32, 64);
  if (lane < 16) out[(size_t)wave * 16 + lane] = dis[wave] * acc;
}

// D=64/128: wave per node, 4-edge unroll (4 independent gather chains in flight).
template <int D>
__global__ void gcn_agg_kernel(const float* __restrict__ h, const int* __restrict__ rowptr,
                               const int* __restrict__ csr, const float* __restrict__ dis,
                               const float* __restrict__ bias, float* __restrict__ out, int n) {
  int wave = (blockIdx.x * blockDim.x + threadIdx.x) >> 6;
  int lane = threadIdx.x & 63;
  if (wave >= n) return;
  int s = rowptr[wave], e = rowptr[wave + 1];
  float a0[4] = {0.f, 0.f, 0.f, 0.f};
  float a1[4] = {0.f, 0.f, 0.f, 0.f};
  int k = s;
  for (; k + 4 <= e; k += 4) {
    int j0 = csr[k], j1 = csr[k + 1], j2 = csr[k + 2], j3 = csr[k + 3];
    float d0 = dis[j0], d1 = dis[j1], d2 = dis[j2], d3 = dis[j3];
    const float* r0 = h + (size_t)j0 * D;
    const float* r1 = h + (size_t)j1 * D;
    const float* r2 = h + (size_t)j2 * D;
    const float* r3 = h + (size_t)j3 * D;
    a0[0] = fmaf(d0, r0[lane], a0[0]);
    a0[1] = fmaf(d1, r1[lane], a0[1]);
    a0[2] = fmaf(d2, r2[lane], a0[2]);
    a0[3] = fmaf(d3, r3[lane], a0[3]);
    if (D == 128) {
      a1[0] = fmaf(d0, r0[lane + 64], a1[0]);
      a1[1] = fmaf(d1, r1[lane + 64], a1[1]);
      a1[2] = fmaf(d2, r2[lane + 64], a1[2]);
      a1[3] = fmaf(d3, r3[lane + 64], a1[3]);
    }
  }
  for (; k < e; ++k) {
    int j0 = csr[k];
    float d0 = dis[j0];
    const float* r0 = h + (size_t)j0 * D;
    a0[0] = fmaf(d0, r0[lane], a0[0]);
    if (D == 128) a1[0] = fmaf(d0, r0[lane + 64], a1[0]);
  }
  float di = dis[wave];
  float b0 = bias ? bias[lane] : 0.f;
  out[(size_t)wave * D + lane] = fmaf(di, (a0[0] + a0[1]) + (a0[2] + a0[3]), b0);
  if (D == 128) {
    float b1 = bias ? bias[lane + 64] : 0.f;
    out[(size_t)wave * D + lane + 64] = fmaf(di, (a1[0] + a1[1]) + (a1[2] + a1[3]), b1);
  }
}

// ---------------- BatchNorm ----------------
template <int D>
__global__ void bn_stats_kernel(const float* __restrict__ x, double* __restrict__ stats, int n) {
  int tid = threadIdx.x;
  int c = tid & (D - 1);
  const int rpb = 256 / D;
  float s1 = 0.f, s2 = 0.f;
  for (int r = blockIdx.x * rpb + tid / D; r < n; r += gridDim.x * rpb) {
    float v = x[(size_t)r * D + c];
    s1 += v;
    s2 = fmaf(v, v, s2);
  }
  atomicAdd(&stats[c], (double)s1);
  atomicAdd(&stats[D + c], (double)s2);
}

template <int D>
__global__ void bn_coef_kernel(const double* __restrict__ stats, const float* __restrict__ g,
                               const float* __restrict__ b, float* __restrict__ coef, int n) {
  int c = threadIdx.x;
  if (c >= D) return;
  double inv_n = 1.0 / (double)n;
  double mu = stats[c] * inv_n;
  double var = stats[D + c] * inv_n - mu * mu;  // biased variance (jnp.var)
  float A = (float)(1.0 / sqrt(var + 1e-5)) * g[c];
  coef[c] = A;
  coef[D + c] = b[c] - (float)mu * A;
}

template <int D, bool ACT>
__global__ void bn_apply_kernel(float* __restrict__ x, const float* __restrict__ coef, int total) {
  int gid = blockIdx.x * blockDim.x + threadIdx.x;
  if (gid >= total) return;
  int c = gid & (D - 1);
  float v = fmaf(x[gid], coef[c], coef[D + c]);
  if (ACT) v = lrelu(v);
  x[gid] = v;
}

// ---------------- GAT ----------------
template <int C>
__global__ void att_coef_kernel(const float* __restrict__ h2, const float* __restrict__ a_src,
                                const float* __restrict__ a_dst, float* __restrict__ asrc,
                                float* __restrict__ adst, int n) {
  int gid = blockIdx.x * blockDim.x + threadIdx.x;
  if (gid >= n * 4) return;
  int nd = gid >> 2, h = gid & 3;
  const float* hr = h2 + (size_t)nd * 4 * C + h * C;
  float s1 = 0.f, s2 = 0.f;
#pragma unroll
  for (int c = 0; c < C; ++c) {
    float v = hr[c];
    s1 = fmaf(v, a_src[h * C + c], s1);
    s2 = fmaf(v, a_dst[h * C + c], s2);
  }
  asrc[gid] = s1;
  adst[gid] = s2;
}

// wave per node; softmax over incoming edges is local (shift-invariant, no max pass).
// 4-edge unroll for memory-level parallelism.
template <int D, int C>
__global__ void gat_agg_kernel(const float* __restrict__ h2, const int* __restrict__ rowptr,
                               const int* __restrict__ csr, const float* __restrict__ asrc,
                               const float* __restrict__ adst, const float* __restrict__ bias,
                               const float* __restrict__ xres, float* __restrict__ out, int n) {
  int wave = (blockIdx.x * blockDim.x + threadIdx.x) >> 6;
  int lane = threadIdx.x & 63;
  if (wave >= n) return;
  const int h0 = lane / C;
  float ad0 = adst[wave * 4 + h0];
  float ad1 = 0.f;
  int h1 = 0;
  if (D == 128) {
    h1 = (lane + 64) / C;
    ad1 = adst[wave * 4 + h1];
  }
  float ac0[4] = {0.f, 0.f, 0.f, 0.f}, ss0[4] = {0.f, 0.f, 0.f, 0.f};
  float ac1[4] = {0.f, 0.f, 0.f, 0.f}, ss1[4] = {0.f, 0.f, 0.f, 0.f};
  int s = rowptr[wave], e = rowptr[wave + 1];
  int k = s;
  for (; k + 4 <= e; k += 4) {
    int j[4] = {csr[k], csr[k + 1], csr[k + 2], csr[k + 3]};
#pragma unroll
    for (int u = 0; u < 4; ++u) {
      const float* r = h2 + (size_t)j[u] * D;
      float ex0 = __expf(lrelu(asrc[j[u] * 4 + h0] + ad0));
      ss0[u] += ex0;
      ac0[u] = fmaf(ex0, r[lane], ac0[u]);
      if (D == 128) {
        float ex1 = __expf(lrelu(asrc[j[u] * 4 + h1] + ad1));
        ss1[u] += ex1;
        ac1[u] = fmaf(ex1, r[lane + 64], ac1[u]);
      }
    }
  }
  for (; k < e; ++k) {
    int j0 = csr[k];
    const float* r = h2 + (size_t)j0 * D;
    float ex0 = __expf(lrelu(asrc[j0 * 4 + h0] + ad0));
    ss0[0] += ex0;
    ac0[0] = fmaf(ex0, r[lane], ac0[0]);
    if (D == 128) {
      float ex1 = __expf(lrelu(asrc[j0 * 4 + h1] + ad1));
      ss1[0] += ex1;
      ac1[0] = fmaf(ex1, r[lane + 64], ac1[0]);
    }
  }
  size_t base = (size_t)wave * D;
  float num0 = (ac0[0] + ac0[1]) + (ac0[2] + ac0[3]);
  float den0 = (ss0[0] + ss0[1]) + (ss0[2] + ss0[3]);
  float v0 = num0 / den0 + bias[lane] + xres[base + lane];
  out[base + lane] = lrelu(v0);
  if (D == 128) {
    float num1 = (ac1[0] + ac1[1]) + (ac1[2] + ac1[3]);
    float den1 = (ss1[0] + ss1[1]) + (ss1[2] + ss1[3]);
    float v1 = num1 / den1 + bias[lane + 64] + xres[base + lane + 64];
    out[base + lane + 64] = lrelu(v1);
  }
}

// ---------------- global mean pool (batch is sorted -> segmented reduce) ----------------
__global__ void graph_bounds_kernel(const int* __restrict__ batch, int* __restrict__ bounds,
                                    int n) {
  int g = threadIdx.x;
  if (g >= GRAPHS) return;
  int lo = 0, hi = n;
  while (lo < hi) {
    int mid = (lo + hi) >> 1;
    if (batch[mid] < g)
      lo = mid + 1;
    else
      hi = mid;
  }
  bounds[g] = lo;
  if (g == 0) bounds[GRAPHS] = n;
}

__global__ void pool_kernel(const float* __restrict__ x, const int* __restrict__ bounds,
                            float* __restrict__ out) {
  __shared__ float sh[4][64];
  int g = blockIdx.x;
  int lane = threadIdx.x & 63, w = threadIdx.x >> 6;
  int s = bounds[g], e = bounds[g + 1];
  float acc = 0.f;
  for (int r = s + w; r < e; r += 4) acc += x[(size_t)r * 64 + lane];
  sh[w][lane] = acc;
  __syncthreads();
  if (w == 0) {
    float t = sh[0][lane] + sh[1][lane] + sh[2][lane] + sh[3][lane];
    out[(g << 6) + lane] = t / fmaxf((float)(e - s), 1.0f);
  }
}

// ---------------- host ----------------
extern "C" void kernel_launch(void* const* d_in, const int* in_sizes, int n_in, void* d_out,
                              int out_size, void* d_ws, size_t ws_size, hipStream_t stream) {
  const float* x_in = (const float*)d_in[0];
  const int* ei = (const int*)d_in[1];
  const int* batch = (const int*)d_in[2];
  const float* gcn_w[4] = {(const float*)d_in[3], (const float*)d_in[7], (const float*)d_in[11],
                           (const float*)d_in[15]};
  const float* gcn_b[4] = {(const float*)d_in[4], (const float*)d_in[8], (const float*)d_in[12],
                           (const float*)d_in[16]};
  const float* bn_g[4] = {(const float*)d_in[5], (const float*)d_in[9], (const float*)d_in[13],
                          (const float*)d_in[17]};
  const float* bn_b[4] = {(const float*)d_in[6], (const float*)d_in[10], (const float*)d_in[14],
                          (const float*)d_in[18]};
  const float* gat_w0 = (const float*)d_in[19];
  const float* gat_as0 = (const float*)d_in[20];
  const float* gat_ad0 = (const float*)d_in[21];
  const float* gat_b0 = (const float*)d_in[22];
  const float* gat_w2 = (const float*)d_in[23];
  const float* gat_as2 = (const float*)d_in[24];
  const float* gat_ad2 = (const float*)d_in[25];
  const float* gat_b2 = (const float*)d_in[26];

  const int N = in_sizes[2];      // 100000
  const int E = in_sizes[1] / 2;  // 1600000

  char* wp = (char*)d_ws;
  auto alloc = [&](size_t bytes) -> void* {
    void* p = (void*)wp;
    wp += (bytes + 255) & ~(size_t)255;
    return p;
  };
  double* stats = (double*)alloc(256 * sizeof(double));
  float* coef = (float*)alloc(256 * sizeof(float));
  int* rowptr = (int*)alloc((size_t)(N + 1) * 4);
  int* cursor = (int*)alloc((size_t)N * 4);
  int* partial = (int*)alloc(256 * sizeof(int));
  int* csr = (int*)alloc((size_t)(N + E) * 4);
  float* dis = (float*)alloc((size_t)N * 4);
  float* bufA = (float*)alloc((size_t)N * 128 * 4);
  float* bufB = (float*)alloc((size_t)N * 128 * 4);
  float* bufC = (float*)alloc((size_t)N * 128 * 4);
  float* attS = (float*)alloc((size_t)N * 4 * 4);
  float* attD = (float*)alloc((size_t)N * 4 * 4);
  int* bounds = (int*)alloc((size_t)(GRAPHS + 1) * 4);
  if ((size_t)(wp - (char*)d_ws) > ws_size) return;

  const int B = 256;
  auto cd = [](int a, int b) { return (a + b - 1) / b; };
  const int scan_blocks = cd(N, SCAN_CHUNK);  // 98 <= 256

  // --- CSR build ---
  init_counts_kernel<<<cd(N, B), B, 0, stream>>>(cursor, N);
  count_edges_kernel<<<cd(E, B), B, 0, stream>>>(ei, cursor, E);
  block_sum_kernel<<<scan_blocks, B, 0, stream>>>(cursor, partial, N);
  partial_scan_kernel<<<1, B, 0, stream>>>(partial, rowptr, scan_blocks, N);
  chunk_scan_kernel<<<scan_blocks, B, 0, stream>>>(cursor, partial, rowptr, N);
  finalize_csr_kernel<<<cd(N, B), B, 0, stream>>>(rowptr, dis, cursor, csr, N);
  fill_edges_kernel<<<cd(E, B), B, 0, stream>>>(ei, cursor, csr, E);
  graph_bounds_kernel<<<1, 256, 0, stream>>>(batch, bounds, N);

  auto bn = [&](float* buf, int D, const float* g, const float* b, bool act) {
    zero_f32_kernel<<<cd(512, B), B, 0, stream>>>((float*)stats, 512);
    if (D == 64) {
      bn_stats_kernel<64><<<256, 256, 0, stream>>>(buf, stats, N);
      bn_coef_kernel<64><<<1, 64, 0, stream>>>(stats, g, b, coef, N);
      int total = N * 64;
      if (act)
        bn_apply_kernel<64, true><<<cd(total, B), B, 0, stream>>>(buf, coef, total);
      else
        bn_apply_kernel<64, false><<<cd(total, B), B, 0, stream>>>(buf, coef, total);
    } else {
      bn_stats_kernel<128><<<256, 256, 0, stream>>>(buf, stats, N);
      bn_coef_kernel<128><<<1, 128, 0, stream>>>(stats, g, b, coef, N);
      int total = N * 128;
      if (act)
        bn_apply_kernel<128, true><<<cd(total, B), B, 0, stream>>>(buf, coef, total);
      else
        bn_apply_kernel<128, false><<<cd(total, B), B, 0, stream>>>(buf, coef, total);
    }
  };

  // ---- Layer 0: GCN 16->64 (aggregate at 16, then transform), BN ----
  gcn_agg16_kernel<<<cd(N * 64, B), B, 0, stream>>>(x_in, rowptr, csr, dis, bufB, N);
  gemm_tile_kernel<16, 64, 8><<<cd(N, 128), B, 0, stream>>>(bufB, gcn_w[0], gcn_b[0], bufC, N);
  bn(bufC, 64, bn_g[0], bn_b[0], false);
  // GAT0 (D=64, C=16) + residual + lrelu -> bufA
  gemm_tile_kernel<64, 64, 8><<<cd(N, 128), B, 0, stream>>>(bufC, gat_w0, nullptr, bufB, N);
  att_coef_kernel<16><<<cd(N * 4, B), B, 0, stream>>>(bufB, gat_as0, gat_ad0, attS, attD, N);
  gat_agg_kernel<64, 16><<<cd(N * 64, B), B, 0, stream>>>(bufB, rowptr, csr, attS, attD, gat_b0,
                                                          bufC, bufA, N);

  // ---- Layer 1: GCN 64->128 (aggregate at 64, then transform), BN + lrelu -> bufC ----
  gcn_agg_kernel<64><<<cd(N * 64, B), B, 0, stream>>>(bufA, rowptr, csr, dis, nullptr, bufB, N);
  gemm_tile_kernel<64, 128, 8><<<cd(N, 64), B, 0, stream>>>(bufB, gcn_w[1], gcn_b[1], bufC, N);
  bn(bufC, 128, bn_g[1], bn_b[1], true);

  // ---- Layer 2: GCN 128->128 (aggregate first), BN ----
  gcn_agg_kernel<128><<<cd(N * 64, B), B, 0, stream>>>(bufC, rowptr, csr, dis, nullptr, bufB, N);
  gemm_tile_kernel<128, 128, 8><<<cd(N, 64), B, 0, stream>>>(bufB, gcn_w[2], gcn_b[2], bufA, N);
  bn(bufA, 128, bn_g[2], bn_b[2], false);
  // GAT2 (D=128, C=32) + residual + lrelu -> bufC
  gemm_tile_kernel<128, 128, 8><<<cd(N, 64), B, 0, stream>>>(bufA, gat_w2, nullptr, bufB, N);
  att_coef_kernel<32><<<cd(N * 4, B), B, 0, stream>>>(bufB, gat_as2, gat_ad2, attS, attD, N);
  gat_agg_kernel<128, 32><<<cd(N * 64, B), B, 0, stream>>>(bufB, rowptr, csr, attS, attD, gat_b2,
                                                           bufA, bufC, N);

  // ---- Layer 3: GCN 128->64 (transform first, aggregate at 64 with bias), BN ----
  gemm_tile_kernel<128, 64, 4><<<cd(N, 64), B, 0, stream>>>(bufC, gcn_w[3], nullptr, bufB, N);
  gcn_agg_kernel<64><<<cd(N * 64, B), B, 0, stream>>>(bufB, rowptr, csr, dis, gcn_b[3], bufA, N);
  bn(bufA, 64, bn_g[3], bn_b[3], false);

  // ---- global mean pool ----
  pool_kernel<<<GRAPHS, 256, 0, stream>>>(bufA, bounds, (float*)d_out);
}

// Round 5
// 1381.008 us; speedup vs baseline: 2.4129x; 1.0819x over previous
//
#include <hip/hip_runtime.h>

static constexpr int GRAPHS = 256;
static constexpr int SCAN_CHUNK = 1024;  // elements per scan block

typedef _Float16 h16;
typedef _Float16 h16x2 __attribute__((ext_vector_type(2)));
typedef _Float16 h16x4 __attribute__((ext_vector_type(4)));

__device__ __forceinline__ float lrelu(float v) { return fmaxf(v, 0.2f * v); }

// ---------------- utility ----------------
__global__ void zero_f32_kernel(float* __restrict__ p, int n) {
  int i = blockIdx.x * blockDim.x + threadIdx.x;
  if (i < n) p[i] = 0.0f;
}

// ---------------- CSR build (target-major adjacency incl. self loops) ----------------
__global__ void init_counts_kernel(int* __restrict__ cnt, int n) {
  int i = blockIdx.x * blockDim.x + threadIdx.x;
  if (i < n) cnt[i] = 1;  // self loop
}

__global__ void count_edges_kernel(const int* __restrict__ ei, int* __restrict__ cnt, int E) {
  int e = blockIdx.x * blockDim.x + threadIdx.x;
  if (e < E) atomicAdd(&cnt[ei[E + e]], 1);  // col = target
}

// ---- 3-phase exclusive scan of counts[0..n) -> rowptr[0..n], rowptr[n]=total ----
__global__ void block_sum_kernel(const int* __restrict__ counts, int* __restrict__ partial,
                                 int n) {
  __shared__ int sh[256];
  int base = blockIdx.x * SCAN_CHUNK;
  int t = threadIdx.x;
  int lim = min(base + SCAN_CHUNK, n);
  int s = 0;
  for (int i = base + t; i < lim; i += 256) s += counts[i];
  sh[t] = s;
  __syncthreads();
  for (int off = 128; off > 0; off >>= 1) {
    if (t < off) sh[t] += sh[t + off];
    __syncthreads();
  }
  if (t == 0) partial[blockIdx.x] = sh[0];
}

__global__ void partial_scan_kernel(int* __restrict__ partial, int* __restrict__ rowptr,
                                    int nblocks, int n) {
  __shared__ int sh[256];
  int t = threadIdx.x;
  int v = (t < nblocks) ? partial[t] : 0;
  sh[t] = v;
  __syncthreads();
  for (int off = 1; off < 256; off <<= 1) {
    int u = (t >= off) ? sh[t - off] : 0;
    __syncthreads();
    sh[t] += u;
    __syncthreads();
  }
  if (t < nblocks) partial[t] = sh[t] - v;  // exclusive
  if (t == 255) rowptr[n] = sh[255];        // grand total
}

__global__ void chunk_scan_kernel(const int* __restrict__ counts, const int* __restrict__ partial,
                                  int* __restrict__ rowptr, int n) {
  __shared__ int sh[256];
  int base = blockIdx.x * SCAN_CHUNK;
  int t = threadIdx.x;
  int i0 = base + t * 4;
  int c0 = 0, c1 = 0, c2 = 0, c3 = 0;
  if (i0 + 3 < n) {
    int4 c = *(const int4*)(counts + i0);
    c0 = c.x;
    c1 = c.y;
    c2 = c.z;
    c3 = c.w;
  } else {
    if (i0 < n) c0 = counts[i0];
    if (i0 + 1 < n) c1 = counts[i0 + 1];
    if (i0 + 2 < n) c2 = counts[i0 + 2];
  }
  int tot = c0 + c1 + c2 + c3;
  sh[t] = tot;
  __syncthreads();
  for (int off = 1; off < 256; off <<= 1) {
    int u = (t >= off) ? sh[t - off] : 0;
    __syncthreads();
    sh[t] += u;
    __syncthreads();
  }
  int run = partial[blockIdx.x] + sh[t] - tot;  // exclusive prefix at i0
  if (i0 < n) { rowptr[i0] = run; run += c0; }
  if (i0 + 1 < n) { rowptr[i0 + 1] = run; run += c1; }
  if (i0 + 2 < n) { rowptr[i0 + 2] = run; run += c2; }
  if (i0 + 3 < n) { rowptr[i0 + 3] = run; }
}

__global__ void finalize_csr_kernel(const int* __restrict__ rowptr, float* __restrict__ dis,
                                    int* __restrict__ cursor, int* __restrict__ csr, int n) {
  int i = blockIdx.x * blockDim.x + threadIdx.x;
  if (i >= n) return;
  int s = rowptr[i], e = rowptr[i + 1];
  dis[i] = rsqrtf((float)(e - s));  // deg includes self loop, >= 1
  csr[s] = i;                       // self loop in slot 0
  cursor[i] = s + 1;
}

__global__ void fill_edges_kernel(const int* __restrict__ ei, int* __restrict__ cursor,
                                  int* __restrict__ csr, int E) {
  int e = blockIdx.x * blockDim.x + threadIdx.x;
  if (e >= E) return;
  int c = ei[E + e];  // target
  int pos = atomicAdd(&cursor[c], 1);
  csr[pos] = ei[e];  // source
}

// ---------------- LDS-tiled GEMM: out[n,c] = sum_k x[n,k]*W[k,c] (+bias), fp16 in/out -----
template <int K, int DOUT, int MT>
__global__ void gemm_tile_kernel(const h16* __restrict__ x, const float* __restrict__ W,
                                 const float* __restrict__ bias, h16* __restrict__ out,
                                 int n_nodes) {
  constexpr int COLG = DOUT / 4;    // threads across columns
  constexpr int ROWG = 256 / COLG;  // node groups
  constexpr int NODES = ROWG * MT;  // nodes per block
  __shared__ float xs[NODES * K];
  int tid = threadIdx.x;
  int node0 = blockIdx.x * NODES;
  int limit = min(NODES, n_nodes - node0);
  // stage x tile (convert fp16 -> fp32), contiguous & coalesced
  const h16x4* src = (const h16x4*)(x + (size_t)node0 * K);
  int tile_q = (limit * K) >> 2;
  for (int i = tid; i < tile_q; i += 256) {
    h16x4 v = src[i];
    float4 f;
    f.x = (float)v[0];
    f.y = (float)v[1];
    f.z = (float)v[2];
    f.w = (float)v[3];
    ((float4*)xs)[i] = f;
  }
  __syncthreads();
  int cg = tid % COLG, rg = tid / COLG;
  int c0 = cg * 4;
  float acc[MT][4];
#pragma unroll
  for (int m = 0; m < MT; ++m)
#pragma unroll
    for (int i = 0; i < 4; ++i) acc[m][i] = 0.f;

  for (int k4 = 0; k4 < K / 4; ++k4) {
    int k = k4 * 4;
    float4 w0 = *(const float4*)(W + (size_t)(k + 0) * DOUT + c0);
    float4 w1 = *(const float4*)(W + (size_t)(k + 1) * DOUT + c0);
    float4 w2 = *(const float4*)(W + (size_t)(k + 2) * DOUT + c0);
    float4 w3 = *(const float4*)(W + (size_t)(k + 3) * DOUT + c0);
#pragma unroll
    for (int m = 0; m < MT; ++m) {
      float4 xv = *(const float4*)(xs + (rg * MT + m) * K + k);
      acc[m][0] = fmaf(xv.x, w0.x, acc[m][0]);
      acc[m][1] = fmaf(xv.x, w0.y, acc[m][1]);
      acc[m][2] = fmaf(xv.x, w0.z, acc[m][2]);
      acc[m][3] = fmaf(xv.x, w0.w, acc[m][3]);
      acc[m][0] = fmaf(xv.y, w1.x, acc[m][0]);
      acc[m][1] = fmaf(xv.y, w1.y, acc[m][1]);
      acc[m][2] = fmaf(xv.y, w1.z, acc[m][2]);
      acc[m][3] = fmaf(xv.y, w1.w, acc[m][3]);
      acc[m][0] = fmaf(xv.z, w2.x, acc[m][0]);
      acc[m][1] = fmaf(xv.z, w2.y, acc[m][1]);
      acc[m][2] = fmaf(xv.z, w2.z, acc[m][2]);
      acc[m][3] = fmaf(xv.z, w2.w, acc[m][3]);
      acc[m][0] = fmaf(xv.w, w3.x, acc[m][0]);
      acc[m][1] = fmaf(xv.w, w3.y, acc[m][1]);
      acc[m][2] = fmaf(xv.w, w3.z, acc[m][2]);
      acc[m][3] = fmaf(xv.w, w3.w, acc[m][3]);
    }
  }
  float4 bv = make_float4(0.f, 0.f, 0.f, 0.f);
  if (bias) bv = *(const float4*)(bias + c0);
#pragma unroll
  for (int m = 0; m < MT; ++m) {
    int node = node0 + rg * MT + m;
    if (node < n_nodes) {
      h16x4 r;
      r[0] = (h16)(acc[m][0] + bv.x);
      r[1] = (h16)(acc[m][1] + bv.y);
      r[2] = (h16)(acc[m][2] + bv.z);
      r[3] = (h16)(acc[m][3] + bv.w);
      *(h16x4*)(out + (size_t)node * DOUT + c0) = r;
    }
  }
}

// ---------------- GCN aggregation (agg commutes with W; fp32 in at D=16, fp16 else) ----
__global__ void gcn_agg16_kernel(const float* __restrict__ h, const int* __restrict__ rowptr,
                                 const int* __restrict__ csr, const float* __restrict__ dis,
                                 h16* __restrict__ out, int n) {
  int wave = (blockIdx.x * blockDim.x + threadIdx.x) >> 6;
  int lane = threadIdx.x & 63;
  if (wave >= n) return;
  int s = rowptr[wave], e = rowptr[wave + 1];
  int q = lane >> 4, c = lane & 15;
  float acc = 0.f;
  for (int k = s + q; k < e; k += 4) {
    int j = csr[k];
    acc = fmaf(dis[j], h[(size_t)j * 16 + c], acc);
  }
  acc += __shfl_xor(acc, 16, 64);
  acc += __shfl_xor(acc, 32, 64);
  if (lane < 16) out[(size_t)wave * 16 + lane] = (h16)(dis[wave] * acc);
}

// D=64: lane = channel; 4-edge unroll.
__global__ void gcn_agg64_kernel(const h16* __restrict__ h, const int* __restrict__ rowptr,
                                 const int* __restrict__ csr, const float* __restrict__ dis,
                                 const float* __restrict__ bias, h16* __restrict__ out, int n) {
  int wave = (blockIdx.x * blockDim.x + threadIdx.x) >> 6;
  int lane = threadIdx.x & 63;
  if (wave >= n) return;
  int s = rowptr[wave], e = rowptr[wave + 1];
  float a[4] = {0.f, 0.f, 0.f, 0.f};
  int k = s;
  for (; k + 4 <= e; k += 4) {
    int j0 = csr[k], j1 = csr[k + 1], j2 = csr[k + 2], j3 = csr[k + 3];
    float d0 = dis[j0], d1 = dis[j1], d2 = dis[j2], d3 = dis[j3];
    float v0 = (float)h[(size_t)j0 * 64 + lane];
    float v1 = (float)h[(size_t)j1 * 64 + lane];
    float v2 = (float)h[(size_t)j2 * 64 + lane];
    float v3 = (float)h[(size_t)j3 * 64 + lane];
    a[0] = fmaf(d0, v0, a[0]);
    a[1] = fmaf(d1, v1, a[1]);
    a[2] = fmaf(d2, v2, a[2]);
    a[3] = fmaf(d3, v3, a[3]);
  }
  for (; k < e; ++k) {
    int j0 = csr[k];
    a[0] = fmaf(dis[j0], (float)h[(size_t)j0 * 64 + lane], a[0]);
  }
  float b0 = bias ? bias[lane] : 0.f;
  out[(size_t)wave * 64 + lane] = (h16)fmaf(dis[wave], (a[0] + a[1]) + (a[2] + a[3]), b0);
}

// D=128: lane owns channels {2l, 2l+1} via packed h16x2; 4-edge unroll.
__global__ void gcn_agg128_kernel(const h16* __restrict__ h, const int* __restrict__ rowptr,
                                  const int* __restrict__ csr, const float* __restrict__ dis,
                                  h16* __restrict__ out, int n) {
  int wave = (blockIdx.x * blockDim.x + threadIdx.x) >> 6;
  int lane = threadIdx.x & 63;
  if (wave >= n) return;
  int s = rowptr[wave], e = rowptr[wave + 1];
  int c2 = lane * 2;
  float a0[4] = {0.f, 0.f, 0.f, 0.f};
  float a1[4] = {0.f, 0.f, 0.f, 0.f};
  int k = s;
  for (; k + 4 <= e; k += 4) {
    int j0 = csr[k], j1 = csr[k + 1], j2 = csr[k + 2], j3 = csr[k + 3];
    float d0 = dis[j0], d1 = dis[j1], d2 = dis[j2], d3 = dis[j3];
    h16x2 v0 = *(const h16x2*)(h + (size_t)j0 * 128 + c2);
    h16x2 v1 = *(const h16x2*)(h + (size_t)j1 * 128 + c2);
    h16x2 v2 = *(const h16x2*)(h + (size_t)j2 * 128 + c2);
    h16x2 v3 = *(const h16x2*)(h + (size_t)j3 * 128 + c2);
    a0[0] = fmaf(d0, (float)v0[0], a0[0]);
    a1[0] = fmaf(d0, (float)v0[1], a1[0]);
    a0[1] = fmaf(d1, (float)v1[0], a0[1]);
    a1[1] = fmaf(d1, (float)v1[1], a1[1]);
    a0[2] = fmaf(d2, (float)v2[0], a0[2]);
    a1[2] = fmaf(d2, (float)v2[1], a1[2]);
    a0[3] = fmaf(d3, (float)v3[0], a0[3]);
    a1[3] = fmaf(d3, (float)v3[1], a1[3]);
  }
  for (; k < e; ++k) {
    int j0 = csr[k];
    float d0 = dis[j0];
    h16x2 v0 = *(const h16x2*)(h + (size_t)j0 * 128 + c2);
    a0[0] = fmaf(d0, (float)v0[0], a0[0]);
    a1[0] = fmaf(d0, (float)v0[1], a1[0]);
  }
  float di = dis[wave];
  h16x2 r;
  r[0] = (h16)(di * ((a0[0] + a0[1]) + (a0[2] + a0[3])));
  r[1] = (h16)(di * ((a1[0] + a1[1]) + (a1[2] + a1[3])));
  *(h16x2*)(out + (size_t)wave * 128 + c2) = r;
}

// ---------------- BatchNorm (fp16 storage, fp32/double math) ----------------
template <int D>
__global__ void bn_stats_kernel(const h16* __restrict__ x, double* __restrict__ stats, int n) {
  int tid = threadIdx.x;
  int c = tid & (D - 1);
  const int rpb = 256 / D;
  float s1 = 0.f, s2 = 0.f;
  for (int r = blockIdx.x * rpb + tid / D; r < n; r += gridDim.x * rpb) {
    float v = (float)x[(size_t)r * D + c];
    s1 += v;
    s2 = fmaf(v, v, s2);
  }
  atomicAdd(&stats[c], (double)s1);
  atomicAdd(&stats[D + c], (double)s2);
}

template <int D>
__global__ void bn_coef_kernel(const double* __restrict__ stats, const float* __restrict__ g,
                               const float* __restrict__ b, float* __restrict__ coef, int n) {
  int c = threadIdx.x;
  if (c >= D) return;
  double inv_n = 1.0 / (double)n;
  double mu = stats[c] * inv_n;
  double var = stats[D + c] * inv_n - mu * mu;  // biased variance (jnp.var)
  float A = (float)(1.0 / sqrt(var + 1e-5)) * g[c];
  coef[c] = A;
  coef[D + c] = b[c] - (float)mu * A;
}

// processes 2 channels (h16x2) per thread
template <int D, bool ACT>
__global__ void bn_apply_kernel(h16* __restrict__ x, const float* __restrict__ coef, int total2) {
  int gid = blockIdx.x * blockDim.x + threadIdx.x;
  if (gid >= total2) return;
  int c0 = (gid * 2) & (D - 1);
  h16x2 v = ((h16x2*)x)[gid];
  float2 A = *(const float2*)(coef + c0);
  float2 Bv = *(const float2*)(coef + D + c0);
  float r0 = fmaf((float)v[0], A.x, Bv.x);
  float r1 = fmaf((float)v[1], A.y, Bv.y);
  if (ACT) {
    r0 = lrelu(r0);
    r1 = lrelu(r1);
  }
  v[0] = (h16)r0;
  v[1] = (h16)r1;
  ((h16x2*)x)[gid] = v;
}

// ---------------- GAT ----------------
template <int C>
__global__ void att_coef_kernel(const h16* __restrict__ h2, const float* __restrict__ a_src,
                                const float* __restrict__ a_dst, float* __restrict__ asrc,
                                float* __restrict__ adst, int n) {
  int gid = blockIdx.x * blockDim.x + threadIdx.x;
  if (gid >= n * 4) return;
  int nd = gid >> 2, h = gid & 3;
  const h16* hr = h2 + (size_t)nd * 4 * C + h * C;
  float s1 = 0.f, s2 = 0.f;
#pragma unroll
  for (int c = 0; c < C; ++c) {
    float v = (float)hr[c];
    s1 = fmaf(v, a_src[h * C + c], s1);
    s2 = fmaf(v, a_dst[h * C + c], s2);
  }
  asrc[gid] = s1;
  adst[gid] = s2;
}

// Per-(edge,head) exp coefficients + per-(node,head) inverse denominators.
// wave per node: lane = 4*edge_sub + head -> coalesced exbuf writes.
__global__ void edge_coef_kernel(const int* __restrict__ rowptr, const int* __restrict__ csr,
                                 const float* __restrict__ asrc, const float* __restrict__ adst,
                                 float* __restrict__ exbuf, float* __restrict__ dinv, int n) {
  int wave = (blockIdx.x * blockDim.x + threadIdx.x) >> 6;
  int lane = threadIdx.x & 63;
  if (wave >= n) return;
  int h = lane & 3, es = lane >> 2;  // 16 edge slots x 4 heads
  float ad = adst[wave * 4 + h];
  int s = rowptr[wave], e = rowptr[wave + 1];
  float den = 0.f;
  for (int k = s + es; k < e; k += 16) {
    int j = csr[k];
    float v = __expf(lrelu(asrc[j * 4 + h] + ad));
    exbuf[(size_t)k * 4 + h] = v;
    den += v;
  }
  den += __shfl_xor(den, 4, 64);
  den += __shfl_xor(den, 8, 64);
  den += __shfl_xor(den, 16, 64);
  den += __shfl_xor(den, 32, 64);
  if (lane < 4) dinv[wave * 4 + h] = 1.0f / den;
}

// D=64,C=16: lane = channel, head = lane>>4. Softmax coefs precomputed.
__global__ void gat_agg64_kernel(const h16* __restrict__ h2, const int* __restrict__ rowptr,
                                 const int* __restrict__ csr, const float* __restrict__ exbuf,
                                 const float* __restrict__ dinv, const float* __restrict__ bias,
                                 const h16* __restrict__ xres, h16* __restrict__ out, int n) {
  int wave = (blockIdx.x * blockDim.x + threadIdx.x) >> 6;
  int lane = threadIdx.x & 63;
  if (wave >= n) return;
  int head = lane >> 4;
  int s = rowptr[wave], e = rowptr[wave + 1];
  float a[4] = {0.f, 0.f, 0.f, 0.f};
  int k = s;
  for (; k + 4 <= e; k += 4) {
    int j0 = csr[k], j1 = csr[k + 1], j2 = csr[k + 2], j3 = csr[k + 3];
    float e0 = exbuf[(size_t)k * 4 + head];
    float e1 = exbuf[(size_t)(k + 1) * 4 + head];
    float e2 = exbuf[(size_t)(k + 2) * 4 + head];
    float e3 = exbuf[(size_t)(k + 3) * 4 + head];
    a[0] = fmaf(e0, (float)h2[(size_t)j0 * 64 + lane], a[0]);
    a[1] = fmaf(e1, (float)h2[(size_t)j1 * 64 + lane], a[1]);
    a[2] = fmaf(e2, (float)h2[(size_t)j2 * 64 + lane], a[2]);
    a[3] = fmaf(e3, (float)h2[(size_t)j3 * 64 + lane], a[3]);
  }
  for (; k < e; ++k) {
    int j0 = csr[k];
    a[0] = fmaf(exbuf[(size_t)k * 4 + head], (float)h2[(size_t)j0 * 64 + lane], a[0]);
  }
  float dv = dinv[wave * 4 + head];
  size_t base = (size_t)wave * 64;
  float v0 = ((a[0] + a[1]) + (a[2] + a[3])) * dv + bias[lane] + (float)xres[base + lane];
  out[base + lane] = (h16)lrelu(v0);
}

// D=128,C=32: lane owns channels {2l,2l+1} -> one head per lane (head = lane>>4).
__global__ void gat_agg128_kernel(const h16* __restrict__ h2, const int* __restrict__ rowptr,
                                  const int* __restrict__ csr, const float* __restrict__ exbuf,
                                  const float* __restrict__ dinv, const float* __restrict__ bias,
                                  const h16* __restrict__ xres, h16* __restrict__ out, int n) {
  int wave = (blockIdx.x * blockDim.x + threadIdx.x) >> 6;
  int lane = threadIdx.x & 63;
  if (wave >= n) return;
  int head = lane >> 4;  // channel 2*lane: (2l)/32 == l/16
  int c2 = lane * 2;
  int s = rowptr[wave], e = rowptr[wave + 1];
  float a0[4] = {0.f, 0.f, 0.f, 0.f};
  float a1[4] = {0.f, 0.f, 0.f, 0.f};
  int k = s;
  for (; k + 4 <= e; k += 4) {
    int j0 = csr[k], j1 = csr[k + 1], j2 = csr[k + 2], j3 = csr[k + 3];
    float e0 = exbuf[(size_t)k * 4 + head];
    float e1 = exbuf[(size_t)(k + 1) * 4 + head];
    float e2 = exbuf[(size_t)(k + 2) * 4 + head];
    float e3 = exbuf[(size_t)(k + 3) * 4 + head];
    h16x2 v0 = *(const h16x2*)(h2 + (size_t)j0 * 128 + c2);
    h16x2 v1 = *(const h16x2*)(h2 + (size_t)j1 * 128 + c2);
    h16x2 v2 = *(const h16x2*)(h2 + (size_t)j2 * 128 + c2);
    h16x2 v3 = *(const h16x2*)(h2 + (size_t)j3 * 128 + c2);
    a0[0] = fmaf(e0, (float)v0[0], a0[0]);
    a1[0] = fmaf(e0, (float)v0[1], a1[0]);
    a0[1] = fmaf(e1, (float)v1[0], a0[1]);
    a1[1] = fmaf(e1, (float)v1[1], a1[1]);
    a0[2] = fmaf(e2, (float)v2[0], a0[2]);
    a1[2] = fmaf(e2, (float)v2[1], a1[2]);
    a0[3] = fmaf(e3, (float)v3[0], a0[3]);
    a1[3] = fmaf(e3, (float)v3[1], a1[3]);
  }
  for (; k < e; ++k) {
    int j0 = csr[k];
    float e0 = exbuf[(size_t)k * 4 + head];
    h16x2 v0 = *(const h16x2*)(h2 + (size_t)j0 * 128 + c2);
    a0[0] = fmaf(e0, (float)v0[0], a0[0]);
    a1[0] = fmaf(e0, (float)v0[1], a1[0]);
  }
  float dv = dinv[wave * 4 + head];
  float2 b2 = *(const float2*)(bias + c2);
  size_t base = (size_t)wave * 128;
  h16x2 xr = *(const h16x2*)(xres + base + c2);
  float v0 = ((a0[0] + a0[1]) + (a0[2] + a0[3])) * dv + b2.x + (float)xr[0];
  float v1 = ((a1[0] + a1[1]) + (a1[2] + a1[3])) * dv + b2.y + (float)xr[1];
  h16x2 r;
  r[0] = (h16)lrelu(v0);
  r[1] = (h16)lrelu(v1);
  *(h16x2*)(out + base + c2) = r;
}

// ---------------- global mean pool (batch is sorted -> segmented reduce) ----------------
__global__ void graph_bounds_kernel(const int* __restrict__ batch, int* __restrict__ bounds,
                                    int n) {
  int g = threadIdx.x;
  if (g >= GRAPHS) return;
  int lo = 0, hi = n;
  while (lo < hi) {
    int mid = (lo + hi) >> 1;
    if (batch[mid] < g)
      lo = mid + 1;
    else
      hi = mid;
  }
  bounds[g] = lo;
  if (g == 0) bounds[GRAPHS] = n;
}

__global__ void pool_kernel(const h16* __restrict__ x, const int* __restrict__ bounds,
                            float* __restrict__ out) {
  __shared__ float sh[4][64];
  int g = blockIdx.x;
  int lane = threadIdx.x & 63, w = threadIdx.x >> 6;
  int s = bounds[g], e = bounds[g + 1];
  float acc = 0.f;
  for (int r = s + w; r < e; r += 4) acc += (float)x[(size_t)r * 64 + lane];
  sh[w][lane] = acc;
  __syncthreads();
  if (w == 0) {
    float t = sh[0][lane] + sh[1][lane] + sh[2][lane] + sh[3][lane];
    out[(g << 6) + lane] = t / fmaxf((float)(e - s), 1.0f);
  }
}

// ---------------- host ----------------
extern "C" void kernel_launch(void* const* d_in, const int* in_sizes, int n_in, void* d_out,
                              int out_size, void* d_ws, size_t ws_size, hipStream_t stream) {
  const float* x_in = (const float*)d_in[0];
  const int* ei = (const int*)d_in[1];
  const int* batch = (const int*)d_in[2];
  const float* gcn_w[4] = {(const float*)d_in[3], (const float*)d_in[7], (const float*)d_in[11],
                           (const float*)d_in[15]};
  const float* gcn_b[4] = {(const float*)d_in[4], (const float*)d_in[8], (const float*)d_in[12],
                           (const float*)d_in[16]};
  const float* bn_g[4] = {(const float*)d_in[5], (const float*)d_in[9], (const float*)d_in[13],
                          (const float*)d_in[17]};
  const float* bn_b[4] = {(const float*)d_in[6], (const float*)d_in[10], (const float*)d_in[14],
                          (const float*)d_in[18]};
  const float* gat_w0 = (const float*)d_in[19];
  const float* gat_as0 = (const float*)d_in[20];
  const float* gat_ad0 = (const float*)d_in[21];
  const float* gat_b0 = (const float*)d_in[22];
  const float* gat_w2 = (const float*)d_in[23];
  const float* gat_as2 = (const float*)d_in[24];
  const float* gat_ad2 = (const float*)d_in[25];
  const float* gat_b2 = (const float*)d_in[26];

  const int N = in_sizes[2];      // 100000
  const int E = in_sizes[1] / 2;  // 1600000

  char* wp = (char*)d_ws;
  auto alloc = [&](size_t bytes) -> void* {
    void* p = (void*)wp;
    wp += (bytes + 255) & ~(size_t)255;
    return p;
  };
  double* stats = (double*)alloc(256 * sizeof(double));
  float* coef = (float*)alloc(256 * sizeof(float));
  int* rowptr = (int*)alloc((size_t)(N + 1) * 4);
  int* cursor = (int*)alloc((size_t)N * 4);
  int* partial = (int*)alloc(256 * sizeof(int));
  int* csr = (int*)alloc((size_t)(N + E) * 4);
  float* dis = (float*)alloc((size_t)N * 4);
  h16* bufA = (h16*)alloc((size_t)N * 128 * 2);
  h16* bufB = (h16*)alloc((size_t)N * 128 * 2);
  h16* bufC = (h16*)alloc((size_t)N * 128 * 2);
  float* attS = (float*)alloc((size_t)N * 4 * 4);
  float* attD = (float*)alloc((size_t)N * 4 * 4);
  float* exbuf = (float*)alloc((size_t)(N + E) * 4 * 4);
  float* dinv = (float*)alloc((size_t)N * 4 * 4);
  int* bounds = (int*)alloc((size_t)(GRAPHS + 1) * 4);
  if ((size_t)(wp - (char*)d_ws) > ws_size) return;

  const int B = 256;
  auto cd = [](int a, int b) { return (a + b - 1) / b; };
  const int scan_blocks = cd(N, SCAN_CHUNK);  // 98 <= 256

  // --- CSR build ---
  init_counts_kernel<<<cd(N, B), B, 0, stream>>>(cursor, N);
  count_edges_kernel<<<cd(E, B), B, 0, stream>>>(ei, cursor, E);
  block_sum_kernel<<<scan_blocks, B, 0, stream>>>(cursor, partial, N);
  partial_scan_kernel<<<1, B, 0, stream>>>(partial, rowptr, scan_blocks, N);
  chunk_scan_kernel<<<scan_blocks, B, 0, stream>>>(cursor, partial, rowptr, N);
  finalize_csr_kernel<<<cd(N, B), B, 0, stream>>>(rowptr, dis, cursor, csr, N);
  fill_edges_kernel<<<cd(E, B), B, 0, stream>>>(ei, cursor, csr, E);
  graph_bounds_kernel<<<1, 256, 0, stream>>>(batch, bounds, N);

  auto bn = [&](h16* buf, int D, const float* g, const float* b, bool act) {
    zero_f32_kernel<<<cd(512, B), B, 0, stream>>>((float*)stats, 512);
    if (D == 64) {
      bn_stats_kernel<64><<<256, 256, 0, stream>>>(buf, stats, N);
      bn_coef_kernel<64><<<1, 64, 0, stream>>>(stats, g, b, coef, N);
      int total2 = N * 32;
      if (act)
        bn_apply_kernel<64, true><<<cd(total2, B), B, 0, stream>>>(buf, coef, total2);
      else
        bn_apply_kernel<64, false><<<cd(total2, B), B, 0, stream>>>(buf, coef, total2);
    } else {
      bn_stats_kernel<128><<<256, 256, 0, stream>>>(buf, stats, N);
      bn_coef_kernel<128><<<1, 128, 0, stream>>>(stats, g, b, coef, N);
      int total2 = N * 64;
      if (act)
        bn_apply_kernel<128, true><<<cd(total2, B), B, 0, stream>>>(buf, coef, total2);
      else
        bn_apply_kernel<128, false><<<cd(total2, B), B, 0, stream>>>(buf, coef, total2);
    }
  };

  // ---- Layer 0: GCN 16->64 (aggregate at 16, then transform), BN ----
  gcn_agg16_kernel<<<cd(N * 64, B), B, 0, stream>>>(x_in, rowptr, csr, dis, bufB, N);
  gemm_tile_kernel<16, 64, 8><<<cd(N, 128), B, 0, stream>>>(bufB, gcn_w[0], gcn_b[0], bufC, N);
  bn(bufC, 64, bn_g[0], bn_b[0], false);
  // GAT0 (D=64, C=16) + residual + lrelu -> bufA
  gemm_tile_kernel<64, 64, 8><<<cd(N, 128), B, 0, stream>>>(bufC, gat_w0, nullptr, bufB, N);
  att_coef_kernel<16><<<cd(N * 4, B), B, 0, stream>>>(bufB, gat_as0, gat_ad0, attS, attD, N);
  edge_coef_kernel<<<cd(N * 64, B), B, 0, stream>>>(rowptr, csr, attS, attD, exbuf, dinv, N);
  gat_agg64_kernel<<<cd(N * 64, B), B, 0, stream>>>(bufB, rowptr, csr, exbuf, dinv, gat_b0, bufC,
                                                    bufA, N);

  // ---- Layer 1: GCN 64->128 (aggregate at 64, then transform), BN + lrelu -> bufC ----
  gcn_agg64_kernel<<<cd(N * 64, B), B, 0, stream>>>(bufA, rowptr, csr, dis, nullptr, bufB, N);
  gemm_tile_kernel<64, 128, 8><<<cd(N, 64), B, 0, stream>>>(bufB, gcn_w[1], gcn_b[1], bufC, N);
  bn(bufC, 128, bn_g[1], bn_b[1], true);

  // ---- Layer 2: GCN 128->128 (aggregate first), BN ----
  gcn_agg128_kernel<<<cd(N * 64, B), B, 0, stream>>>(bufC, rowptr, csr, dis, bufB, N);
  gemm_tile_kernel<128, 128, 8><<<cd(N, 64), B, 0, stream>>>(bufB, gcn_w[2], gcn_b[2], bufA, N);
  bn(bufA, 128, bn_g[2], bn_b[2], false);
  // GAT2 (D=128, C=32) + residual + lrelu -> bufC
  gemm_tile_kernel<128, 128, 8><<<cd(N, 64), B, 0, stream>>>(bufA, gat_w2, nullptr, bufB, N);
  att_coef_kernel<32><<<cd(N * 4, B), B, 0, stream>>>(bufB, gat_as2, gat_ad2, attS, attD, N);
  edge_coef_kernel<<<cd(N * 64, B), B, 0, stream>>>(rowptr, csr, attS, attD, exbuf, dinv, N);
  gat_agg128_kernel<<<cd(N * 64, B), B, 0, stream>>>(bufB, rowptr, csr, exbuf, dinv, gat_b2, bufA,
                                                     bufC, N);

  // ---- Layer 3: GCN 128->64 (transform first, aggregate at 64 with bias), BN ----
  gemm_tile_kernel<128, 64, 4><<<cd(N, 64), B, 0, stream>>>(bufC, gcn_w[3], nullptr, bufB, N);
  gcn_agg64_kernel<<<cd(N * 64, B), B, 0, stream>>>(bufB, rowptr, csr, dis, gcn_b[3], bufA, N);
  bn(bufA, 64, bn_g[3], bn_b[3], false);

  // ---- global mean pool ----
  pool_kernel<<<GRAPHS, 256, 0, stream>>>(bufA, bounds, (float*)d_out);
}

// Round 6
// 1332.712 us; speedup vs baseline: 2.5003x; 1.0362x over previous
//
#include <hip/hip_runtime.h>

static constexpr int GRAPHS = 256;
static constexpr int SCAN_CHUNK = 1024;  // elements per scan block
static constexpr int XCDS = 8;

typedef _Float16 h16;
typedef _Float16 h16x2 __attribute__((ext_vector_type(2)));
typedef _Float16 h16x4 __attribute__((ext_vector_type(4)));

__device__ __forceinline__ float lrelu(float v) { return fmaxf(v, 0.2f * v); }

// ---------------- utility ----------------
__global__ void zero_f32_kernel(float* __restrict__ p, int n) {
  int i = blockIdx.x * blockDim.x + threadIdx.x;
  if (i < n) p[i] = 0.0f;
}

// ---------------- CSR build (target-major adjacency incl. self loops) ----------------
__global__ void init_counts_kernel(int* __restrict__ cnt, int n) {
  int i = blockIdx.x * blockDim.x + threadIdx.x;
  if (i < n) cnt[i] = 1;  // self loop
}

__global__ void count_edges_kernel(const int* __restrict__ ei, int* __restrict__ cnt, int E) {
  int e = blockIdx.x * blockDim.x + threadIdx.x;
  if (e < E) atomicAdd(&cnt[ei[E + e]], 1);  // col = target
}

// ---- 3-phase exclusive scan of counts[0..n) -> rowptr[0..n], rowptr[n]=total ----
__global__ void block_sum_kernel(const int* __restrict__ counts, int* __restrict__ partial,
                                 int n) {
  __shared__ int sh[256];
  int base = blockIdx.x * SCAN_CHUNK;
  int t = threadIdx.x;
  int lim = min(base + SCAN_CHUNK, n);
  int s = 0;
  for (int i = base + t; i < lim; i += 256) s += counts[i];
  sh[t] = s;
  __syncthreads();
  for (int off = 128; off > 0; off >>= 1) {
    if (t < off) sh[t] += sh[t + off];
    __syncthreads();
  }
  if (t == 0) partial[blockIdx.x] = sh[0];
}

__global__ void partial_scan_kernel(int* __restrict__ partial, int* __restrict__ rowptr,
                                    int nblocks, int n) {
  __shared__ int sh[256];
  int t = threadIdx.x;
  int v = (t < nblocks) ? partial[t] : 0;
  sh[t] = v;
  __syncthreads();
  for (int off = 1; off < 256; off <<= 1) {
    int u = (t >= off) ? sh[t - off] : 0;
    __syncthreads();
    sh[t] += u;
    __syncthreads();
  }
  if (t < nblocks) partial[t] = sh[t] - v;  // exclusive
  if (t == 255) rowptr[n] = sh[255];        // grand total
}

__global__ void chunk_scan_kernel(const int* __restrict__ counts, const int* __restrict__ partial,
                                  int* __restrict__ rowptr, int n) {
  __shared__ int sh[256];
  int base = blockIdx.x * SCAN_CHUNK;
  int t = threadIdx.x;
  int i0 = base + t * 4;
  int c0 = 0, c1 = 0, c2 = 0, c3 = 0;
  if (i0 + 3 < n) {
    int4 c = *(const int4*)(counts + i0);
    c0 = c.x;
    c1 = c.y;
    c2 = c.z;
    c3 = c.w;
  } else {
    if (i0 < n) c0 = counts[i0];
    if (i0 + 1 < n) c1 = counts[i0 + 1];
    if (i0 + 2 < n) c2 = counts[i0 + 2];
  }
  int tot = c0 + c1 + c2 + c3;
  sh[t] = tot;
  __syncthreads();
  for (int off = 1; off < 256; off <<= 1) {
    int u = (t >= off) ? sh[t - off] : 0;
    __syncthreads();
    sh[t] += u;
    __syncthreads();
  }
  int run = partial[blockIdx.x] + sh[t] - tot;  // exclusive prefix at i0
  if (i0 < n) { rowptr[i0] = run; run += c0; }
  if (i0 + 1 < n) { rowptr[i0 + 1] = run; run += c1; }
  if (i0 + 2 < n) { rowptr[i0 + 2] = run; run += c2; }
  if (i0 + 3 < n) { rowptr[i0 + 3] = run; }
}

__global__ void finalize_csr_kernel(const int* __restrict__ rowptr, float* __restrict__ dis,
                                    int* __restrict__ cursor, int* __restrict__ csr, int n) {
  int i = blockIdx.x * blockDim.x + threadIdx.x;
  if (i >= n) return;
  int s = rowptr[i], e = rowptr[i + 1];
  dis[i] = rsqrtf((float)(e - s));  // deg includes self loop, >= 1
  csr[s] = i;                       // self loop in slot 0
  cursor[i] = s + 1;
}

// XCD-bucketed fill: bucket p covers targets [p*nb, (p+1)*nb). All blocks writing
// bucket p have blockIdx % 8 == p -> same XCD (round-robin heuristic) -> csr write
// window (~850 KB) accumulates FULL sectors in that XCD's L2 before eviction,
// avoiding partial-sector HBM write RMW. Correct regardless of the mapping.
__global__ void fill_edges_kernel(const int* __restrict__ ei, int* __restrict__ cursor,
                                  int* __restrict__ csr, int E, int nb) {
  int p = blockIdx.x & (XCDS - 1);
  int lo = p * nb, hi = lo + nb;
  int nchunks = gridDim.x >> 3;
  int chunk = blockIdx.x >> 3;
  int stride = nchunks * blockDim.x;
  for (int e = chunk * blockDim.x + threadIdx.x; e < E; e += stride) {
    int c = ei[E + e];  // target
    if (c >= lo && c < hi) {
      int pos = atomicAdd(&cursor[c], 1);
      csr[pos] = ei[e];  // source
    }
  }
}

// ---------------- LDS-tiled GEMM: out[n,c] = sum_k x[n,k]*W[k,c] (+bias), fp16 in/out -----
template <int K, int DOUT, int MT>
__global__ void gemm_tile_kernel(const h16* __restrict__ x, const float* __restrict__ W,
                                 const float* __restrict__ bias, h16* __restrict__ out,
                                 int n_nodes) {
  constexpr int COLG = DOUT / 4;    // threads across columns
  constexpr int ROWG = 256 / COLG;  // node groups
  constexpr int NODES = ROWG * MT;  // nodes per block
  __shared__ float xs[NODES * K];
  int tid = threadIdx.x;
  int node0 = blockIdx.x * NODES;
  int limit = min(NODES, n_nodes - node0);
  // stage x tile (convert fp16 -> fp32), contiguous & coalesced
  const h16x4* src = (const h16x4*)(x + (size_t)node0 * K);
  int tile_q = (limit * K) >> 2;
  for (int i = tid; i < tile_q; i += 256) {
    h16x4 v = src[i];
    float4 f;
    f.x = (float)v[0];
    f.y = (float)v[1];
    f.z = (float)v[2];
    f.w = (float)v[3];
    ((float4*)xs)[i] = f;
  }
  __syncthreads();
  int cg = tid % COLG, rg = tid / COLG;
  int c0 = cg * 4;
  float acc[MT][4];
#pragma unroll
  for (int m = 0; m < MT; ++m)
#pragma unroll
    for (int i = 0; i < 4; ++i) acc[m][i] = 0.f;

  for (int k4 = 0; k4 < K / 4; ++k4) {
    int k = k4 * 4;
    float4 w0 = *(const float4*)(W + (size_t)(k + 0) * DOUT + c0);
    float4 w1 = *(const float4*)(W + (size_t)(k + 1) * DOUT + c0);
    float4 w2 = *(const float4*)(W + (size_t)(k + 2) * DOUT + c0);
    float4 w3 = *(const float4*)(W + (size_t)(k + 3) * DOUT + c0);
#pragma unroll
    for (int m = 0; m < MT; ++m) {
      float4 xv = *(const float4*)(xs + (rg * MT + m) * K + k);
      acc[m][0] = fmaf(xv.x, w0.x, acc[m][0]);
      acc[m][1] = fmaf(xv.x, w0.y, acc[m][1]);
      acc[m][2] = fmaf(xv.x, w0.z, acc[m][2]);
      acc[m][3] = fmaf(xv.x, w0.w, acc[m][3]);
      acc[m][0] = fmaf(xv.y, w1.x, acc[m][0]);
      acc[m][1] = fmaf(xv.y, w1.y, acc[m][1]);
      acc[m][2] = fmaf(xv.y, w1.z, acc[m][2]);
      acc[m][3] = fmaf(xv.y, w1.w, acc[m][3]);
      acc[m][0] = fmaf(xv.z, w2.x, acc[m][0]);
      acc[m][1] = fmaf(xv.z, w2.y, acc[m][1]);
      acc[m][2] = fmaf(xv.z, w2.z, acc[m][2]);
      acc[m][3] = fmaf(xv.z, w2.w, acc[m][3]);
      acc[m][0] = fmaf(xv.w, w3.x, acc[m][0]);
      acc[m][1] = fmaf(xv.w, w3.y, acc[m][1]);
      acc[m][2] = fmaf(xv.w, w3.z, acc[m][2]);
      acc[m][3] = fmaf(xv.w, w3.w, acc[m][3]);
    }
  }
  float4 bv = make_float4(0.f, 0.f, 0.f, 0.f);
  if (bias) bv = *(const float4*)(bias + c0);
#pragma unroll
  for (int m = 0; m < MT; ++m) {
    int node = node0 + rg * MT + m;
    if (node < n_nodes) {
      h16x4 r;
      r[0] = (h16)(acc[m][0] + bv.x);
      r[1] = (h16)(acc[m][1] + bv.y);
      r[2] = (h16)(acc[m][2] + bv.z);
      r[3] = (h16)(acc[m][3] + bv.w);
      *(h16x4*)(out + (size_t)node * DOUT + c0) = r;
    }
  }
}

// ---------------- GCN aggregation (agg commutes with W; fp32 in at D=16, fp16 else) ----
__global__ void gcn_agg16_kernel(const float* __restrict__ h, const int* __restrict__ rowptr,
                                 const int* __restrict__ csr, const float* __restrict__ dis,
                                 h16* __restrict__ out, int n) {
  int wave = (blockIdx.x * blockDim.x + threadIdx.x) >> 6;
  int lane = threadIdx.x & 63;
  if (wave >= n) return;
  int s = rowptr[wave], e = rowptr[wave + 1];
  int q = lane >> 4, c = lane & 15;
  float acc = 0.f;
  for (int k = s + q; k < e; k += 4) {
    int j = csr[k];
    acc = fmaf(dis[j], h[(size_t)j * 16 + c], acc);
  }
  acc += __shfl_xor(acc, 16, 64);
  acc += __shfl_xor(acc, 32, 64);
  if (lane < 16) out[(size_t)wave * 16 + lane] = (h16)(dis[wave] * acc);
}

// D=64: lane = channel; 4-edge unroll.
__global__ void gcn_agg64_kernel(const h16* __restrict__ h, const int* __restrict__ rowptr,
                                 const int* __restrict__ csr, const float* __restrict__ dis,
                                 const float* __restrict__ bias, h16* __restrict__ out, int n) {
  int wave = (blockIdx.x * blockDim.x + threadIdx.x) >> 6;
  int lane = threadIdx.x & 63;
  if (wave >= n) return;
  int s = rowptr[wave], e = rowptr[wave + 1];
  float a[4] = {0.f, 0.f, 0.f, 0.f};
  int k = s;
  for (; k + 4 <= e; k += 4) {
    int j0 = csr[k], j1 = csr[k + 1], j2 = csr[k + 2], j3 = csr[k + 3];
    float d0 = dis[j0], d1 = dis[j1], d2 = dis[j2], d3 = dis[j3];
    float v0 = (float)h[(size_t)j0 * 64 + lane];
    float v1 = (float)h[(size_t)j1 * 64 + lane];
    float v2 = (float)h[(size_t)j2 * 64 + lane];
    float v3 = (float)h[(size_t)j3 * 64 + lane];
    a[0] = fmaf(d0, v0, a[0]);
    a[1] = fmaf(d1, v1, a[1]);
    a[2] = fmaf(d2, v2, a[2]);
    a[3] = fmaf(d3, v3, a[3]);
  }
  for (; k < e; ++k) {
    int j0 = csr[k];
    a[0] = fmaf(dis[j0], (float)h[(size_t)j0 * 64 + lane], a[0]);
  }
  float b0 = bias ? bias[lane] : 0.f;
  out[(size_t)wave * 64 + lane] = (h16)fmaf(dis[wave], (a[0] + a[1]) + (a[2] + a[3]), b0);
}

// D=128: lane owns channels {2l, 2l+1} via packed h16x2; 4-edge unroll.
__global__ void gcn_agg128_kernel(const h16* __restrict__ h, const int* __restrict__ rowptr,
                                  const int* __restrict__ csr, const float* __restrict__ dis,
                                  h16* __restrict__ out, int n) {
  int wave = (blockIdx.x * blockDim.x + threadIdx.x) >> 6;
  int lane = threadIdx.x & 63;
  if (wave >= n) return;
  int s = rowptr[wave], e = rowptr[wave + 1];
  int c2 = lane * 2;
  float a0[4] = {0.f, 0.f, 0.f, 0.f};
  float a1[4] = {0.f, 0.f, 0.f, 0.f};
  int k = s;
  for (; k + 4 <= e; k += 4) {
    int j0 = csr[k], j1 = csr[k + 1], j2 = csr[k + 2], j3 = csr[k + 3];
    float d0 = dis[j0], d1 = dis[j1], d2 = dis[j2], d3 = dis[j3];
    h16x2 v0 = *(const h16x2*)(h + (size_t)j0 * 128 + c2);
    h16x2 v1 = *(const h16x2*)(h + (size_t)j1 * 128 + c2);
    h16x2 v2 = *(const h16x2*)(h + (size_t)j2 * 128 + c2);
    h16x2 v3 = *(const h16x2*)(h + (size_t)j3 * 128 + c2);
    a0[0] = fmaf(d0, (float)v0[0], a0[0]);
    a1[0] = fmaf(d0, (float)v0[1], a1[0]);
    a0[1] = fmaf(d1, (float)v1[0], a0[1]);
    a1[1] = fmaf(d1, (float)v1[1], a1[1]);
    a0[2] = fmaf(d2, (float)v2[0], a0[2]);
    a1[2] = fmaf(d2, (float)v2[1], a1[2]);
    a0[3] = fmaf(d3, (float)v3[0], a0[3]);
    a1[3] = fmaf(d3, (float)v3[1], a1[3]);
  }
  for (; k < e; ++k) {
    int j0 = csr[k];
    float d0 = dis[j0];
    h16x2 v0 = *(const h16x2*)(h + (size_t)j0 * 128 + c2);
    a0[0] = fmaf(d0, (float)v0[0], a0[0]);
    a1[0] = fmaf(d0, (float)v0[1], a1[0]);
  }
  float di = dis[wave];
  h16x2 r;
  r[0] = (h16)(di * ((a0[0] + a0[1]) + (a0[2] + a0[3])));
  r[1] = (h16)(di * ((a1[0] + a1[1]) + (a1[2] + a1[3])));
  *(h16x2*)(out + (size_t)wave * 128 + c2) = r;
}

// ---------------- BatchNorm (fp16 storage, fp32/double math) ----------------
template <int D>
__global__ void bn_stats_kernel(const h16* __restrict__ x, double* __restrict__ stats, int n) {
  int tid = threadIdx.x;
  int c = tid & (D - 1);
  const int rpb = 256 / D;
  float s1 = 0.f, s2 = 0.f;
  for (int r = blockIdx.x * rpb + tid / D; r < n; r += gridDim.x * rpb) {
    float v = (float)x[(size_t)r * D + c];
    s1 += v;
    s2 = fmaf(v, v, s2);
  }
  atomicAdd(&stats[c], (double)s1);
  atomicAdd(&stats[D + c], (double)s2);
}

template <int D>
__global__ void bn_coef_kernel(const double* __restrict__ stats, const float* __restrict__ g,
                               const float* __restrict__ b, float* __restrict__ coef, int n) {
  int c = threadIdx.x;
  if (c >= D) return;
  double inv_n = 1.0 / (double)n;
  double mu = stats[c] * inv_n;
  double var = stats[D + c] * inv_n - mu * mu;  // biased variance (jnp.var)
  float A = (float)(1.0 / sqrt(var + 1e-5)) * g[c];
  coef[c] = A;
  coef[D + c] = b[c] - (float)mu * A;
}

// processes 2 channels (h16x2) per thread
template <int D, bool ACT>
__global__ void bn_apply_kernel(h16* __restrict__ x, const float* __restrict__ coef, int total2) {
  int gid = blockIdx.x * blockDim.x + threadIdx.x;
  if (gid >= total2) return;
  int c0 = (gid * 2) & (D - 1);
  h16x2 v = ((h16x2*)x)[gid];
  float2 A = *(const float2*)(coef + c0);
  float2 Bv = *(const float2*)(coef + D + c0);
  float r0 = fmaf((float)v[0], A.x, Bv.x);
  float r1 = fmaf((float)v[1], A.y, Bv.y);
  if (ACT) {
    r0 = lrelu(r0);
    r1 = lrelu(r1);
  }
  v[0] = (h16)r0;
  v[1] = (h16)r1;
  ((h16x2*)x)[gid] = v;
}

// ---------------- GAT ----------------
template <int C>
__global__ void att_coef_kernel(const h16* __restrict__ h2, const float* __restrict__ a_src,
                                const float* __restrict__ a_dst, float* __restrict__ asrc,
                                float* __restrict__ adst, int n) {
  int gid = blockIdx.x * blockDim.x + threadIdx.x;
  if (gid >= n * 4) return;
  int nd = gid >> 2, h = gid & 3;
  const h16* hr = h2 + (size_t)nd * 4 * C + h * C;
  float s1 = 0.f, s2 = 0.f;
#pragma unroll
  for (int c = 0; c < C; ++c) {
    float v = (float)hr[c];
    s1 = fmaf(v, a_src[h * C + c], s1);
    s2 = fmaf(v, a_dst[h * C + c], s2);
  }
  asrc[gid] = s1;
  adst[gid] = s2;
}

// Per-(edge,head) exp coefficients + per-(node,head) inverse denominators.
__global__ void edge_coef_kernel(const int* __restrict__ rowptr, const int* __restrict__ csr,
                                 const float* __restrict__ asrc, const float* __restrict__ adst,
                                 float* __restrict__ exbuf, float* __restrict__ dinv, int n) {
  int wave = (blockIdx.x * blockDim.x + threadIdx.x) >> 6;
  int lane = threadIdx.x & 63;
  if (wave >= n) return;
  int h = lane & 3, es = lane >> 2;  // 16 edge slots x 4 heads
  float ad = adst[wave * 4 + h];
  int s = rowptr[wave], e = rowptr[wave + 1];
  float den = 0.f;
  for (int k = s + es; k < e; k += 16) {
    int j = csr[k];
    float v = __expf(lrelu(asrc[j * 4 + h] + ad));
    exbuf[(size_t)k * 4 + h] = v;
    den += v;
  }
  den += __shfl_xor(den, 4, 64);
  den += __shfl_xor(den, 8, 64);
  den += __shfl_xor(den, 16, 64);
  den += __shfl_xor(den, 32, 64);
  if (lane < 4) dinv[wave * 4 + h] = 1.0f / den;
}

// D=64,C=16: lane = channel, head = lane>>4. Softmax coefs precomputed.
__global__ void gat_agg64_kernel(const h16* __restrict__ h2, const int* __restrict__ rowptr,
                                 const int* __restrict__ csr, const float* __restrict__ exbuf,
                                 const float* __restrict__ dinv, const float* __restrict__ bias,
                                 const h16* __restrict__ xres, h16* __restrict__ out, int n) {
  int wave = (blockIdx.x * blockDim.x + threadIdx.x) >> 6;
  int lane = threadIdx.x & 63;
  if (wave >= n) return;
  int head = lane >> 4;
  int s = rowptr[wave], e = rowptr[wave + 1];
  float a[4] = {0.f, 0.f, 0.f, 0.f};
  int k = s;
  for (; k + 4 <= e; k += 4) {
    int j0 = csr[k], j1 = csr[k + 1], j2 = csr[k + 2], j3 = csr[k + 3];
    float e0 = exbuf[(size_t)k * 4 + head];
    float e1 = exbuf[(size_t)(k + 1) * 4 + head];
    float e2 = exbuf[(size_t)(k + 2) * 4 + head];
    float e3 = exbuf[(size_t)(k + 3) * 4 + head];
    a[0] = fmaf(e0, (float)h2[(size_t)j0 * 64 + lane], a[0]);
    a[1] = fmaf(e1, (float)h2[(size_t)j1 * 64 + lane], a[1]);
    a[2] = fmaf(e2, (float)h2[(size_t)j2 * 64 + lane], a[2]);
    a[3] = fmaf(e3, (float)h2[(size_t)j3 * 64 + lane], a[3]);
  }
  for (; k < e; ++k) {
    int j0 = csr[k];
    a[0] = fmaf(exbuf[(size_t)k * 4 + head], (float)h2[(size_t)j0 * 64 + lane], a[0]);
  }
  float dv = dinv[wave * 4 + head];
  size_t base = (size_t)wave * 64;
  float v0 = ((a[0] + a[1]) + (a[2] + a[3])) * dv + bias[lane] + (float)xres[base + lane];
  out[base + lane] = (h16)lrelu(v0);
}

// D=128,C=32: lane owns channels {2l,2l+1} -> one head per lane (head = lane>>4).
__global__ void gat_agg128_kernel(const h16* __restrict__ h2, const int* __restrict__ rowptr,
                                  const int* __restrict__ csr, const float* __restrict__ exbuf,
                                  const float* __restrict__ dinv, const float* __restrict__ bias,
                                  const h16* __restrict__ xres, h16* __restrict__ out, int n) {
  int wave = (blockIdx.x * blockDim.x + threadIdx.x) >> 6;
  int lane = threadIdx.x & 63;
  if (wave >= n) return;
  int head = lane >> 4;  // channel 2*lane: (2l)/32 == l/16
  int c2 = lane * 2;
  int s = rowptr[wave], e = rowptr[wave + 1];
  float a0[4] = {0.f, 0.f, 0.f, 0.f};
  float a1[4] = {0.f, 0.f, 0.f, 0.f};
  int k = s;
  for (; k + 4 <= e; k += 4) {
    int j0 = csr[k], j1 = csr[k + 1], j2 = csr[k + 2], j3 = csr[k + 3];
    float e0 = exbuf[(size_t)k * 4 + head];
    float e1 = exbuf[(size_t)(k + 1) * 4 + head];
    float e2 = exbuf[(size_t)(k + 2) * 4 + head];
    float e3 = exbuf[(size_t)(k + 3) * 4 + head];
    h16x2 v0 = *(const h16x2*)(h2 + (size_t)j0 * 128 + c2);
    h16x2 v1 = *(const h16x2*)(h2 + (size_t)j1 * 128 + c2);
    h16x2 v2 = *(const h16x2*)(h2 + (size_t)j2 * 128 + c2);
    h16x2 v3 = *(const h16x2*)(h2 + (size_t)j3 * 128 + c2);
    a0[0] = fmaf(e0, (float)v0[0], a0[0]);
    a1[0] = fmaf(e0, (float)v0[1], a1[0]);
    a0[1] = fmaf(e1, (float)v1[0], a0[1]);
    a1[1] = fmaf(e1, (float)v1[1], a1[1]);
    a0[2] = fmaf(e2, (float)v2[0], a0[2]);
    a1[2] = fmaf(e2, (float)v2[1], a1[2]);
    a0[3] = fmaf(e3, (float)v3[0], a0[3]);
    a1[3] = fmaf(e3, (float)v3[1], a1[3]);
  }
  for (; k < e; ++k) {
    int j0 = csr[k];
    float e0 = exbuf[(size_t)k * 4 + head];
    h16x2 v0 = *(const h16x2*)(h2 + (size_t)j0 * 128 + c2);
    a0[0] = fmaf(e0, (float)v0[0], a0[0]);
    a1[0] = fmaf(e0, (float)v0[1], a1[0]);
  }
  float dv = dinv[wave * 4 + head];
  float2 b2 = *(const float2*)(bias + c2);
  size_t base = (size_t)wave * 128;
  h16x2 xr = *(const h16x2*)(xres + base + c2);
  float v0 = ((a0[0] + a0[1]) + (a0[2] + a0[3])) * dv + b2.x + (float)xr[0];
  float v1 = ((a1[0] + a1[1]) + (a1[2] + a1[3])) * dv + b2.y + (float)xr[1];
  h16x2 r;
  r[0] = (h16)lrelu(v0);
  r[1] = (h16)lrelu(v1);
  *(h16x2*)(out + base + c2) = r;
}

// ---------------- global mean pool (batch is sorted -> segmented reduce) ----------------
__global__ void graph_bounds_kernel(const int* __restrict__ batch, int* __restrict__ bounds,
                                    int n) {
  int g = threadIdx.x;
  if (g >= GRAPHS) return;
  int lo = 0, hi = n;
  while (lo < hi) {
    int mid = (lo + hi) >> 1;
    if (batch[mid] < g)
      lo = mid + 1;
    else
      hi = mid;
  }
  bounds[g] = lo;
  if (g == 0) bounds[GRAPHS] = n;
}

__global__ void pool_kernel(const h16* __restrict__ x, const int* __restrict__ bounds,
                            float* __restrict__ out) {
  __shared__ float sh[4][64];
  int g = blockIdx.x;
  int lane = threadIdx.x & 63, w = threadIdx.x >> 6;
  int s = bounds[g], e = bounds[g + 1];
  float acc = 0.f;
  for (int r = s + w; r < e; r += 4) acc += (float)x[(size_t)r * 64 + lane];
  sh[w][lane] = acc;
  __syncthreads();
  if (w == 0) {
    float t = sh[0][lane] + sh[1][lane] + sh[2][lane] + sh[3][lane];
    out[(g << 6) + lane] = t / fmaxf((float)(e - s), 1.0f);
  }
}

// ---------------- host ----------------
extern "C" void kernel_launch(void* const* d_in, const int* in_sizes, int n_in, void* d_out,
                              int out_size, void* d_ws, size_t ws_size, hipStream_t stream) {
  const float* x_in = (const float*)d_in[0];
  const int* ei = (const int*)d_in[1];
  const int* batch = (const int*)d_in[2];
  const float* gcn_w[4] = {(const float*)d_in[3], (const float*)d_in[7], (const float*)d_in[11],
                           (const float*)d_in[15]};
  const float* gcn_b[4] = {(const float*)d_in[4], (const float*)d_in[8], (const float*)d_in[12],
                           (const float*)d_in[16]};
  const float* bn_g[4] = {(const float*)d_in[5], (const float*)d_in[9], (const float*)d_in[13],
                          (const float*)d_in[17]};
  const float* bn_b[4] = {(const float*)d_in[6], (const float*)d_in[10], (const float*)d_in[14],
                          (const float*)d_in[18]};
  const float* gat_w0 = (const float*)d_in[19];
  const float* gat_as0 = (const float*)d_in[20];
  const float* gat_ad0 = (const float*)d_in[21];
  const float* gat_b0 = (const float*)d_in[22];
  const float* gat_w2 = (const float*)d_in[23];
  const float* gat_as2 = (const float*)d_in[24];
  const float* gat_ad2 = (const float*)d_in[25];
  const float* gat_b2 = (const float*)d_in[26];

  const int N = in_sizes[2];      // 100000
  const int E = in_sizes[1] / 2;  // 1600000

  char* wp = (char*)d_ws;
  auto alloc = [&](size_t bytes) -> void* {
    void* p = (void*)wp;
    wp += (bytes + 255) & ~(size_t)255;
    return p;
  };
  double* stats = (double*)alloc(256 * sizeof(double));
  float* coef = (float*)alloc(256 * sizeof(float));
  int* rowptr = (int*)alloc((size_t)(N + 1) * 4);
  int* cursor = (int*)alloc((size_t)N * 4);
  int* partial = (int*)alloc(256 * sizeof(int));
  int* csr = (int*)alloc((size_t)(N + E) * 4);
  float* dis = (float*)alloc((size_t)N * 4);
  h16* bufA = (h16*)alloc((size_t)N * 128 * 2);
  h16* bufB = (h16*)alloc((size_t)N * 128 * 2);
  h16* bufC = (h16*)alloc((size_t)N * 128 * 2);
  float* attS = (float*)alloc((size_t)N * 4 * 4);
  float* attD = (float*)alloc((size_t)N * 4 * 4);
  float* exbuf = (float*)alloc((size_t)(N + E) * 4 * 4);
  float* dinv = (float*)alloc((size_t)N * 4 * 4);
  int* bounds = (int*)alloc((size_t)(GRAPHS + 1) * 4);
  if ((size_t)(wp - (char*)d_ws) > ws_size) return;

  const int B = 256;
  auto cd = [](int a, int b) { return (a + b - 1) / b; };
  const int scan_blocks = cd(N, SCAN_CHUNK);  // 98 <= 256

  // --- CSR build ---
  init_counts_kernel<<<cd(N, B), B, 0, stream>>>(cursor, N);
  count_edges_kernel<<<cd(E, B), B, 0, stream>>>(ei, cursor, E);
  block_sum_kernel<<<scan_blocks, B, 0, stream>>>(cursor, partial, N);
  partial_scan_kernel<<<1, B, 0, stream>>>(partial, rowptr, scan_blocks, N);
  chunk_scan_kernel<<<scan_blocks, B, 0, stream>>>(cursor, partial, rowptr, N);
  finalize_csr_kernel<<<cd(N, B), B, 0, stream>>>(rowptr, dis, cursor, csr, N);
  {
    int nb = cd(N, XCDS);  // nodes per bucket
    fill_edges_kernel<<<XCDS * 512, B, 0, stream>>>(ei, cursor, csr, E, nb);
  }
  graph_bounds_kernel<<<1, 256, 0, stream>>>(batch, bounds, N);

  auto bn = [&](h16* buf, int D, const float* g, const float* b, bool act) {
    zero_f32_kernel<<<cd(512, B), B, 0, stream>>>((float*)stats, 512);
    if (D == 64) {
      bn_stats_kernel<64><<<256, 256, 0, stream>>>(buf, stats, N);
      bn_coef_kernel<64><<<1, 64, 0, stream>>>(stats, g, b, coef, N);
      int total2 = N * 32;
      if (act)
        bn_apply_kernel<64, true><<<cd(total2, B), B, 0, stream>>>(buf, coef, total2);
      else
        bn_apply_kernel<64, false><<<cd(total2, B), B, 0, stream>>>(buf, coef, total2);
    } else {
      bn_stats_kernel<128><<<256, 256, 0, stream>>>(buf, stats, N);
      bn_coef_kernel<128><<<1, 128, 0, stream>>>(stats, g, b, coef, N);
      int total2 = N * 64;
      if (act)
        bn_apply_kernel<128, true><<<cd(total2, B), B, 0, stream>>>(buf, coef, total2);
      else
        bn_apply_kernel<128, false><<<cd(total2, B), B, 0, stream>>>(buf, coef, total2);
    }
  };

  // ---- Layer 0: GCN 16->64 (aggregate at 16, then transform), BN ----
  gcn_agg16_kernel<<<cd(N * 64, B), B, 0, stream>>>(x_in, rowptr, csr, dis, bufB, N);
  gemm_tile_kernel<16, 64, 8><<<cd(N, 128), B, 0, stream>>>(bufB, gcn_w[0], gcn_b[0], bufC, N);
  bn(bufC, 64, bn_g[0], bn_b[0], false);
  // GAT0 (D=64, C=16) + residual + lrelu -> bufA
  gemm_tile_kernel<64, 64, 8><<<cd(N, 128), B, 0, stream>>>(bufC, gat_w0, nullptr, bufB, N);
  att_coef_kernel<16><<<cd(N * 4, B), B, 0, stream>>>(bufB, gat_as0, gat_ad0, attS, attD, N);
  edge_coef_kernel<<<cd(N * 64, B), B, 0, stream>>>(rowptr, csr, attS, attD, exbuf, dinv, N);
  gat_agg64_kernel<<<cd(N * 64, B), B, 0, stream>>>(bufB, rowptr, csr, exbuf, dinv, gat_b0, bufC,
                                                    bufA, N);

  // ---- Layer 1: GCN 64->128 (aggregate at 64, then transform), BN + lrelu -> bufC ----
  gcn_agg64_kernel<<<cd(N * 64, B), B, 0, stream>>>(bufA, rowptr, csr, dis, nullptr, bufB, N);
  gemm_tile_kernel<64, 128, 8><<<cd(N, 64), B, 0, stream>>>(bufB, gcn_w[1], gcn_b[1], bufC, N);
  bn(bufC, 128, bn_g[1], bn_b[1], true);

  // ---- Layer 2: GCN 128->128 (aggregate first), BN ----
  gcn_agg128_kernel<<<cd(N * 64, B), B, 0, stream>>>(bufC, rowptr, csr, dis, bufB, N);
  gemm_tile_kernel<128, 128, 8><<<cd(N, 64), B, 0, stream>>>(bufB, gcn_w[2], gcn_b[2], bufA, N);
  bn(bufA, 128, bn_g[2], bn_b[2], false);
  // GAT2 (D=128, C=32) + residual + lrelu -> bufC
  gemm_tile_kernel<128, 128, 8><<<cd(N, 64), B, 0, stream>>>(bufA, gat_w2, nullptr, bufB, N);
  att_coef_kernel<32><<<cd(N * 4, B), B, 0, stream>>>(bufB, gat_as2, gat_ad2, attS, attD, N);
  edge_coef_kernel<<<cd(N * 64, B), B, 0, stream>>>(rowptr, csr, attS, attD, exbuf, dinv, N);
  gat_agg128_kernel<<<cd(N * 64, B), B, 0, stream>>>(bufB, rowptr, csr, exbuf, dinv, gat_b2, bufA,
                                                     bufC, N);

  // ---- Layer 3: GCN 128->64 (transform first, aggregate at 64 with bias), BN ----
  gemm_tile_kernel<128, 64, 4><<<cd(N, 64), B, 0, stream>>>(bufC, gcn_w[3], nullptr, bufB, N);
  gcn_agg64_kernel<<<cd(N * 64, B), B, 0, stream>>>(bufB, rowptr, csr, dis, gcn_b[3], bufA, N);
  bn(bufA, 64, bn_g[3], bn_b[3], false);

  // ---- global mean pool ----
  pool_kernel<<<GRAPHS, 256, 0, stream>>>(bufA, bounds, (float*)d_out);
}

// Round 7
// 1246.779 us; speedup vs baseline: 2.6727x; 1.0689x over previous
//
#include <hip/hip_runtime.h>

static constexpr int GRAPHS = 256;
static constexpr int SCAN_CHUNK = 1024;  // elements per scan block
static constexpr int XCDS = 8;

typedef _Float16 h16;
typedef _Float16 h16x2 __attribute__((ext_vector_type(2)));
typedef _Float16 h16x4 __attribute__((ext_vector_type(4)));

__device__ __forceinline__ float lrelu(float v) { return fmaxf(v, 0.2f * v); }
__device__ __forceinline__ int rfl(int v) { return __builtin_amdgcn_readfirstlane(v); }

// ---------------- utility ----------------
__global__ void zero_f32_kernel(float* __restrict__ p, int n) {
  int i = blockIdx.x * blockDim.x + threadIdx.x;
  if (i < n) p[i] = 0.0f;
}

// ---------------- CSR build (target-major adjacency incl. self loops) ----------------
__global__ void init_counts_kernel(int* __restrict__ cnt, int n) {
  int i = blockIdx.x * blockDim.x + threadIdx.x;
  if (i < n) cnt[i] = 1;  // self loop
}

__global__ void count_edges_kernel(const int* __restrict__ ei, int* __restrict__ cnt, int E) {
  int e = blockIdx.x * blockDim.x + threadIdx.x;
  if (e < E) atomicAdd(&cnt[ei[E + e]], 1);  // col = target
}

// ---- 3-phase exclusive scan of counts[0..n) -> rowptr[0..n], rowptr[n]=total ----
__global__ void block_sum_kernel(const int* __restrict__ counts, int* __restrict__ partial,
                                 int n) {
  __shared__ int sh[256];
  int base = blockIdx.x * SCAN_CHUNK;
  int t = threadIdx.x;
  int lim = min(base + SCAN_CHUNK, n);
  int s = 0;
  for (int i = base + t; i < lim; i += 256) s += counts[i];
  sh[t] = s;
  __syncthreads();
  for (int off = 128; off > 0; off >>= 1) {
    if (t < off) sh[t] += sh[t + off];
    __syncthreads();
  }
  if (t == 0) partial[blockIdx.x] = sh[0];
}

__global__ void partial_scan_kernel(int* __restrict__ partial, int* __restrict__ rowptr,
                                    int nblocks, int n) {
  __shared__ int sh[256];
  int t = threadIdx.x;
  int v = (t < nblocks) ? partial[t] : 0;
  sh[t] = v;
  __syncthreads();
  for (int off = 1; off < 256; off <<= 1) {
    int u = (t >= off) ? sh[t - off] : 0;
    __syncthreads();
    sh[t] += u;
    __syncthreads();
  }
  if (t < nblocks) partial[t] = sh[t] - v;  // exclusive
  if (t == 255) rowptr[n] = sh[255];        // grand total
}

__global__ void chunk_scan_kernel(const int* __restrict__ counts, const int* __restrict__ partial,
                                  int* __restrict__ rowptr, int n) {
  __shared__ int sh[256];
  int base = blockIdx.x * SCAN_CHUNK;
  int t = threadIdx.x;
  int i0 = base + t * 4;
  int c0 = 0, c1 = 0, c2 = 0, c3 = 0;
  if (i0 + 3 < n) {
    int4 c = *(const int4*)(counts + i0);
    c0 = c.x;
    c1 = c.y;
    c2 = c.z;
    c3 = c.w;
  } else {
    if (i0 < n) c0 = counts[i0];
    if (i0 + 1 < n) c1 = counts[i0 + 1];
    if (i0 + 2 < n) c2 = counts[i0 + 2];
  }
  int tot = c0 + c1 + c2 + c3;
  sh[t] = tot;
  __syncthreads();
  for (int off = 1; off < 256; off <<= 1) {
    int u = (t >= off) ? sh[t - off] : 0;
    __syncthreads();
    sh[t] += u;
    __syncthreads();
  }
  int run = partial[blockIdx.x] + sh[t] - tot;  // exclusive prefix at i0
  if (i0 < n) { rowptr[i0] = run; run += c0; }
  if (i0 + 1 < n) { rowptr[i0 + 1] = run; run += c1; }
  if (i0 + 2 < n) { rowptr[i0 + 2] = run; run += c2; }
  if (i0 + 3 < n) { rowptr[i0 + 3] = run; }
}

__global__ void finalize_csr_kernel(const int* __restrict__ rowptr, float* __restrict__ dis,
                                    int* __restrict__ cursor, int* __restrict__ csr, int n) {
  int i = blockIdx.x * blockDim.x + threadIdx.x;
  if (i >= n) return;
  int s = rowptr[i], e = rowptr[i + 1];
  dis[i] = rsqrtf((float)(e - s));  // deg includes self loop, >= 1
  csr[s] = i;                       // self loop in slot 0
  cursor[i] = s + 1;
}

// XCD-bucketed fill (avoids partial-sector HBM write RMW; see r6 post-mortem).
__global__ void fill_edges_kernel(const int* __restrict__ ei, int* __restrict__ cursor,
                                  int* __restrict__ csr, int E, int nb) {
  int p = blockIdx.x & (XCDS - 1);
  int lo = p * nb, hi = lo + nb;
  int nchunks = gridDim.x >> 3;
  int chunk = blockIdx.x >> 3;
  int stride = nchunks * blockDim.x;
  for (int e = chunk * blockDim.x + threadIdx.x; e < E; e += stride) {
    int c = ei[E + e];  // target
    if (c >= lo && c < hi) {
      int pos = atomicAdd(&cursor[c], 1);
      csr[pos] = ei[e];  // source
    }
  }
}

// ---------------- LDS-tiled GEMM: out[n,c] = sum_k x[n,k]*W[k,c] (+bias), fp16 in/out -----
template <int K, int DOUT, int MT>
__global__ void gemm_tile_kernel(const h16* __restrict__ x, const float* __restrict__ W,
                                 const float* __restrict__ bias, h16* __restrict__ out,
                                 int n_nodes) {
  constexpr int COLG = DOUT / 4;    // threads across columns
  constexpr int ROWG = 256 / COLG;  // node groups
  constexpr int NODES = ROWG * MT;  // nodes per block
  __shared__ float xs[NODES * K];
  int tid = threadIdx.x;
  int node0 = blockIdx.x * NODES;
  int limit = min(NODES, n_nodes - node0);
  const h16x4* src = (const h16x4*)(x + (size_t)node0 * K);
  int tile_q = (limit * K) >> 2;
  for (int i = tid; i < tile_q; i += 256) {
    h16x4 v = src[i];
    float4 f;
    f.x = (float)v[0];
    f.y = (float)v[1];
    f.z = (float)v[2];
    f.w = (float)v[3];
    ((float4*)xs)[i] = f;
  }
  __syncthreads();
  int cg = tid % COLG, rg = tid / COLG;
  int c0 = cg * 4;
  float acc[MT][4];
#pragma unroll
  for (int m = 0; m < MT; ++m)
#pragma unroll
    for (int i = 0; i < 4; ++i) acc[m][i] = 0.f;

  for (int k4 = 0; k4 < K / 4; ++k4) {
    int k = k4 * 4;
    float4 w0 = *(const float4*)(W + (size_t)(k + 0) * DOUT + c0);
    float4 w1 = *(const float4*)(W + (size_t)(k + 1) * DOUT + c0);
    float4 w2 = *(const float4*)(W + (size_t)(k + 2) * DOUT + c0);
    float4 w3 = *(const float4*)(W + (size_t)(k + 3) * DOUT + c0);
#pragma unroll
    for (int m = 0; m < MT; ++m) {
      float4 xv = *(const float4*)(xs + (rg * MT + m) * K + k);
      acc[m][0] = fmaf(xv.x, w0.x, acc[m][0]);
      acc[m][1] = fmaf(xv.x, w0.y, acc[m][1]);
      acc[m][2] = fmaf(xv.x, w0.z, acc[m][2]);
      acc[m][3] = fmaf(xv.x, w0.w, acc[m][3]);
      acc[m][0] = fmaf(xv.y, w1.x, acc[m][0]);
      acc[m][1] = fmaf(xv.y, w1.y, acc[m][1]);
      acc[m][2] = fmaf(xv.y, w1.z, acc[m][2]);
      acc[m][3] = fmaf(xv.y, w1.w, acc[m][3]);
      acc[m][0] = fmaf(xv.z, w2.x, acc[m][0]);
      acc[m][1] = fmaf(xv.z, w2.y, acc[m][1]);
      acc[m][2] = fmaf(xv.z, w2.z, acc[m][2]);
      acc[m][3] = fmaf(xv.z, w2.w, acc[m][3]);
      acc[m][0] = fmaf(xv.w, w3.x, acc[m][0]);
      acc[m][1] = fmaf(xv.w, w3.y, acc[m][1]);
      acc[m][2] = fmaf(xv.w, w3.z, acc[m][2]);
      acc[m][3] = fmaf(xv.w, w3.w, acc[m][3]);
    }
  }
  float4 bv = make_float4(0.f, 0.f, 0.f, 0.f);
  if (bias) bv = *(const float4*)(bias + c0);
#pragma unroll
  for (int m = 0; m < MT; ++m) {
    int node = node0 + rg * MT + m;
    if (node < n_nodes) {
      h16x4 r;
      r[0] = (h16)(acc[m][0] + bv.x);
      r[1] = (h16)(acc[m][1] + bv.y);
      r[2] = (h16)(acc[m][2] + bv.z);
      r[3] = (h16)(acc[m][3] + bv.w);
      *(h16x4*)(out + (size_t)node * DOUT + c0) = r;
    }
  }
}

// ---------------- GCN aggregation (agg commutes with W; fp32 in at D=16, fp16 else) ----
__global__ void gcn_agg16_kernel(const float* __restrict__ h, const int* __restrict__ rowptr,
                                 const int* __restrict__ csr, const float* __restrict__ dis,
                                 h16* __restrict__ out, int n) {
  int wave = (blockIdx.x * blockDim.x + threadIdx.x) >> 6;
  int lane = threadIdx.x & 63;
  if (wave >= n) return;
  int s = rowptr[wave], e = rowptr[wave + 1];
  int q = lane >> 4, c = lane & 15;
  float acc = 0.f;
  for (int k = s + q; k < e; k += 4) {
    int j = csr[k];
    acc = fmaf(dis[j], h[(size_t)j * 16 + c], acc);
  }
  acc += __shfl_xor(acc, 16, 64);
  acc += __shfl_xor(acc, 32, 64);
  if (lane < 16) out[(size_t)wave * 16 + lane] = (h16)(dis[wave] * acc);
}

// D=64: lane = channel; wave-uniform indices scalarized, 8-edge unroll.
__global__ void gcn_agg64_kernel(const h16* __restrict__ h, const int* __restrict__ rowptr,
                                 const int* __restrict__ csr, const float* __restrict__ dis,
                                 const float* __restrict__ bias, h16* __restrict__ out, int n) {
  int wave = (blockIdx.x * blockDim.x + threadIdx.x) >> 6;
  int lane = threadIdx.x & 63;
  if (wave >= n) return;
  int s = rfl(rowptr[wave]);
  int e = rfl(rowptr[wave + 1]);
  float a[4] = {0.f, 0.f, 0.f, 0.f};
  int k = s;
  for (; k + 8 <= e; k += 8) {
    int j[8];
    float d[8];
#pragma unroll
    for (int u = 0; u < 8; ++u) j[u] = rfl(csr[k + u]);
#pragma unroll
    for (int u = 0; u < 8; ++u) d[u] = dis[j[u]];
#pragma unroll
    for (int u = 0; u < 8; ++u) {
      const h16* rp = h + (size_t)j[u] * 64;  // uniform base, lane offset
      a[u & 3] = fmaf(d[u], (float)rp[lane], a[u & 3]);
    }
  }
  for (; k + 4 <= e; k += 4) {
    int j[4];
#pragma unroll
    for (int u = 0; u < 4; ++u) j[u] = rfl(csr[k + u]);
#pragma unroll
    for (int u = 0; u < 4; ++u) {
      const h16* rp = h + (size_t)j[u] * 64;
      a[u] = fmaf(dis[j[u]], (float)rp[lane], a[u]);
    }
  }
  for (; k < e; ++k) {
    int j0 = rfl(csr[k]);
    const h16* rp = h + (size_t)j0 * 64;
    a[0] = fmaf(dis[j0], (float)rp[lane], a[0]);
  }
  float b0 = bias ? bias[lane] : 0.f;
  out[(size_t)wave * 64 + lane] = (h16)fmaf(dis[wave], (a[0] + a[1]) + (a[2] + a[3]), b0);
}

// D=128: lane owns channels {2l, 2l+1}; scalarized indices, 8-edge unroll.
__global__ void gcn_agg128_kernel(const h16* __restrict__ h, const int* __restrict__ rowptr,
                                  const int* __restrict__ csr, const float* __restrict__ dis,
                                  h16* __restrict__ out, int n) {
  int wave = (blockIdx.x * blockDim.x + threadIdx.x) >> 6;
  int lane = threadIdx.x & 63;
  if (wave >= n) return;
  int s = rfl(rowptr[wave]);
  int e = rfl(rowptr[wave + 1]);
  int c2 = lane * 2;
  float a0[4] = {0.f, 0.f, 0.f, 0.f};
  float a1[4] = {0.f, 0.f, 0.f, 0.f};
  int k = s;
  for (; k + 8 <= e; k += 8) {
    int j[8];
    float d[8];
#pragma unroll
    for (int u = 0; u < 8; ++u) j[u] = rfl(csr[k + u]);
#pragma unroll
    for (int u = 0; u < 8; ++u) d[u] = dis[j[u]];
#pragma unroll
    for (int u = 0; u < 8; ++u) {
      const h16* rp = h + (size_t)j[u] * 128;
      h16x2 v = *(const h16x2*)(rp + c2);
      a0[u & 3] = fmaf(d[u], (float)v[0], a0[u & 3]);
      a1[u & 3] = fmaf(d[u], (float)v[1], a1[u & 3]);
    }
  }
  for (; k + 4 <= e; k += 4) {
    int j[4];
#pragma unroll
    for (int u = 0; u < 4; ++u) j[u] = rfl(csr[k + u]);
#pragma unroll
    for (int u = 0; u < 4; ++u) {
      const h16* rp = h + (size_t)j[u] * 128;
      h16x2 v = *(const h16x2*)(rp + c2);
      a0[u] = fmaf(dis[j[u]], (float)v[0], a0[u]);
      a1[u] = fmaf(dis[j[u]], (float)v[1], a1[u]);
    }
  }
  for (; k < e; ++k) {
    int j0 = rfl(csr[k]);
    const h16* rp = h + (size_t)j0 * 128;
    h16x2 v = *(const h16x2*)(rp + c2);
    a0[0] = fmaf(dis[j0], (float)v[0], a0[0]);
    a1[0] = fmaf(dis[j0], (float)v[1], a1[0]);
  }
  float di = dis[wave];
  h16x2 r;
  r[0] = (h16)(di * ((a0[0] + a0[1]) + (a0[2] + a0[3])));
  r[1] = (h16)(di * ((a1[0] + a1[1]) + (a1[2] + a1[3])));
  *(h16x2*)(out + (size_t)wave * 128 + c2) = r;
}

// ---------------- BatchNorm (fp16 storage, fp32/double math) ----------------
template <int D>
__global__ void bn_stats_kernel(const h16* __restrict__ x, double* __restrict__ stats, int n) {
  int tid = threadIdx.x;
  int c = tid & (D - 1);
  const int rpb = 256 / D;
  float s1 = 0.f, s2 = 0.f;
  for (int r = blockIdx.x * rpb + tid / D; r < n; r += gridDim.x * rpb) {
    float v = (float)x[(size_t)r * D + c];
    s1 += v;
    s2 = fmaf(v, v, s2);
  }
  atomicAdd(&stats[c], (double)s1);
  atomicAdd(&stats[D + c], (double)s2);
}

template <int D>
__global__ void bn_coef_kernel(const double* __restrict__ stats, const float* __restrict__ g,
                               const float* __restrict__ b, float* __restrict__ coef, int n) {
  int c = threadIdx.x;
  if (c >= D) return;
  double inv_n = 1.0 / (double)n;
  double mu = stats[c] * inv_n;
  double var = stats[D + c] * inv_n - mu * mu;  // biased variance (jnp.var)
  float A = (float)(1.0 / sqrt(var + 1e-5)) * g[c];
  coef[c] = A;
  coef[D + c] = b[c] - (float)mu * A;
}

// processes 2 channels (h16x2) per thread
template <int D, bool ACT>
__global__ void bn_apply_kernel(h16* __restrict__ x, const float* __restrict__ coef, int total2) {
  int gid = blockIdx.x * blockDim.x + threadIdx.x;
  if (gid >= total2) return;
  int c0 = (gid * 2) & (D - 1);
  h16x2 v = ((h16x2*)x)[gid];
  float2 A = *(const float2*)(coef + c0);
  float2 Bv = *(const float2*)(coef + D + c0);
  float r0 = fmaf((float)v[0], A.x, Bv.x);
  float r1 = fmaf((float)v[1], A.y, Bv.y);
  if (ACT) {
    r0 = lrelu(r0);
    r1 = lrelu(r1);
  }
  v[0] = (h16)r0;
  v[1] = (h16)r1;
  ((h16x2*)x)[gid] = v;
}

// ---------------- GAT ----------------
template <int C>
__global__ void att_coef_kernel(const h16* __restrict__ h2, const float* __restrict__ a_src,
                                const float* __restrict__ a_dst, float* __restrict__ asrc,
                                float* __restrict__ adst, int n) {
  int gid = blockIdx.x * blockDim.x + threadIdx.x;
  if (gid >= n * 4) return;
  int nd = gid >> 2, h = gid & 3;
  const h16* hr = h2 + (size_t)nd * 4 * C + h * C;
  float s1 = 0.f, s2 = 0.f;
#pragma unroll
  for (int c = 0; c < C; ++c) {
    float v = (float)hr[c];
    s1 = fmaf(v, a_src[h * C + c], s1);
    s2 = fmaf(v, a_dst[h * C + c], s2);
  }
  asrc[gid] = s1;
  adst[gid] = s2;
}

// Per-(edge,head) exp coefficients + per-(node,head) inverse denominators.
__global__ void edge_coef_kernel(const int* __restrict__ rowptr, const int* __restrict__ csr,
                                 const float* __restrict__ asrc, const float* __restrict__ adst,
                                 float* __restrict__ exbuf, float* __restrict__ dinv, int n) {
  int wave = (blockIdx.x * blockDim.x + threadIdx.x) >> 6;
  int lane = threadIdx.x & 63;
  if (wave >= n) return;
  int h = lane & 3, es = lane >> 2;  // 16 edge slots x 4 heads
  float ad = adst[wave * 4 + h];
  int s = rowptr[wave], e = rowptr[wave + 1];
  float den = 0.f;
  for (int k = s + es; k < e; k += 16) {
    int j = csr[k];
    float v = __expf(lrelu(asrc[j * 4 + h] + ad));
    exbuf[(size_t)k * 4 + h] = v;
    den += v;
  }
  den += __shfl_xor(den, 4, 64);
  den += __shfl_xor(den, 8, 64);
  den += __shfl_xor(den, 16, 64);
  den += __shfl_xor(den, 32, 64);
  if (lane < 4) dinv[wave * 4 + h] = 1.0f / den;
}

// D=64,C=16: lane = channel, head = lane>>4; scalarized indices, 8-edge unroll.
__global__ void gat_agg64_kernel(const h16* __restrict__ h2, const int* __restrict__ rowptr,
                                 const int* __restrict__ csr, const float* __restrict__ exbuf,
                                 const float* __restrict__ dinv, const float* __restrict__ bias,
                                 const h16* __restrict__ xres, h16* __restrict__ out, int n) {
  int wave = (blockIdx.x * blockDim.x + threadIdx.x) >> 6;
  int lane = threadIdx.x & 63;
  if (wave >= n) return;
  int head = lane >> 4;
  int s = rfl(rowptr[wave]);
  int e = rfl(rowptr[wave + 1]);
  float a[4] = {0.f, 0.f, 0.f, 0.f};
  int k = s;
  for (; k + 8 <= e; k += 8) {
    int j[8];
    float ex[8];
#pragma unroll
    for (int u = 0; u < 8; ++u) {
      j[u] = rfl(csr[k + u]);
      ex[u] = exbuf[(size_t)(k + u) * 4 + head];
    }
#pragma unroll
    for (int u = 0; u < 8; ++u) {
      const h16* rp = h2 + (size_t)j[u] * 64;
      a[u & 3] = fmaf(ex[u], (float)rp[lane], a[u & 3]);
    }
  }
  for (; k + 4 <= e; k += 4) {
    int j[4];
    float ex[4];
#pragma unroll
    for (int u = 0; u < 4; ++u) {
      j[u] = rfl(csr[k + u]);
      ex[u] = exbuf[(size_t)(k + u) * 4 + head];
    }
#pragma unroll
    for (int u = 0; u < 4; ++u) {
      const h16* rp = h2 + (size_t)j[u] * 64;
      a[u] = fmaf(ex[u], (float)rp[lane], a[u]);
    }
  }
  for (; k < e; ++k) {
    int j0 = rfl(csr[k]);
    const h16* rp = h2 + (size_t)j0 * 64;
    a[0] = fmaf(exbuf[(size_t)k * 4 + head], (float)rp[lane], a[0]);
  }
  float dv = dinv[wave * 4 + head];
  size_t base = (size_t)wave * 64;
  float v0 = ((a[0] + a[1]) + (a[2] + a[3])) * dv + bias[lane] + (float)xres[base + lane];
  out[base + lane] = (h16)lrelu(v0);
}

// D=128,C=32: lane owns channels {2l,2l+1} (one head/lane); scalarized, 8-edge unroll.
__global__ void gat_agg128_kernel(const h16* __restrict__ h2, const int* __restrict__ rowptr,
                                  const int* __restrict__ csr, const float* __restrict__ exbuf,
                                  const float* __restrict__ dinv, const float* __restrict__ bias,
                                  const h16* __restrict__ xres, h16* __restrict__ out, int n) {
  int wave = (blockIdx.x * blockDim.x + threadIdx.x) >> 6;
  int lane = threadIdx.x & 63;
  if (wave >= n) return;
  int head = lane >> 4;
  int c2 = lane * 2;
  int s = rfl(rowptr[wave]);
  int e = rfl(rowptr[wave + 1]);
  float a0[4] = {0.f, 0.f, 0.f, 0.f};
  float a1[4] = {0.f, 0.f, 0.f, 0.f};
  int k = s;
  for (; k + 8 <= e; k += 8) {
    int j[8];
    float ex[8];
#pragma unroll
    for (int u = 0; u < 8; ++u) {
      j[u] = rfl(csr[k + u]);
      ex[u] = exbuf[(size_t)(k + u) * 4 + head];
    }
#pragma unroll
    for (int u = 0; u < 8; ++u) {
      const h16* rp = h2 + (size_t)j[u] * 128;
      h16x2 v = *(const h16x2*)(rp + c2);
      a0[u & 3] = fmaf(ex[u], (float)v[0], a0[u & 3]);
      a1[u & 3] = fmaf(ex[u], (float)v[1], a1[u & 3]);
    }
  }
  for (; k + 4 <= e; k += 4) {
    int j[4];
    float ex[4];
#pragma unroll
    for (int u = 0; u < 4; ++u) {
      j[u] = rfl(csr[k + u]);
      ex[u] = exbuf[(size_t)(k + u) * 4 + head];
    }
#pragma unroll
    for (int u = 0; u < 4; ++u) {
      const h16* rp = h2 + (size_t)j[u] * 128;
      h16x2 v = *(const h16x2*)(rp + c2);
      a0[u] = fmaf(ex[u], (float)v[0], a0[u]);
      a1[u] = fmaf(ex[u], (float)v[1], a1[u]);
    }
  }
  for (; k < e; ++k) {
    int j0 = rfl(csr[k]);
    float e0 = exbuf[(size_t)k * 4 + head];
    const h16* rp = h2 + (size_t)j0 * 128;
    h16x2 v = *(const h16x2*)(rp + c2);
    a0[0] = fmaf(e0, (float)v[0], a0[0]);
    a1[0] = fmaf(e0, (float)v[1], a1[0]);
  }
  float dv = dinv[wave * 4 + head];
  float2 b2 = *(const float2*)(bias + c2);
  size_t base = (size_t)wave * 128;
  h16x2 xr = *(const h16x2*)(xres + base + c2);
  float v0 = ((a0[0] + a0[1]) + (a0[2] + a0[3])) * dv + b2.x + (float)xr[0];
  float v1 = ((a1[0] + a1[1]) + (a1[2] + a1[3])) * dv + b2.y + (float)xr[1];
  h16x2 r;
  r[0] = (h16)lrelu(v0);
  r[1] = (h16)lrelu(v1);
  *(h16x2*)(out + base + c2) = r;
}

// ---------------- global mean pool (batch is sorted -> segmented reduce) ----------------
__global__ void graph_bounds_kernel(const int* __restrict__ batch, int* __restrict__ bounds,
                                    int n) {
  int g = threadIdx.x;
  if (g >= GRAPHS) return;
  int lo = 0, hi = n;
  while (lo < hi) {
    int mid = (lo + hi) >> 1;
    if (batch[mid] < g)
      lo = mid + 1;
    else
      hi = mid;
  }
  bounds[g] = lo;
  if (g == 0) bounds[GRAPHS] = n;
}

__global__ void pool_kernel(const h16* __restrict__ x, const int* __restrict__ bounds,
                            float* __restrict__ out) {
  __shared__ float sh[4][64];
  int g = blockIdx.x;
  int lane = threadIdx.x & 63, w = threadIdx.x >> 6;
  int s = bounds[g], e = bounds[g + 1];
  float acc = 0.f;
  for (int r = s + w; r < e; r += 4) acc += (float)x[(size_t)r * 64 + lane];
  sh[w][lane] = acc;
  __syncthreads();
  if (w == 0) {
    float t = sh[0][lane] + sh[1][lane] + sh[2][lane] + sh[3][lane];
    out[(g << 6) + lane] = t / fmaxf((float)(e - s), 1.0f);
  }
}

// ---------------- host ----------------
extern "C" void kernel_launch(void* const* d_in, const int* in_sizes, int n_in, void* d_out,
                              int out_size, void* d_ws, size_t ws_size, hipStream_t stream) {
  const float* x_in = (const float*)d_in[0];
  const int* ei = (const int*)d_in[1];
  const int* batch = (const int*)d_in[2];
  const float* gcn_w[4] = {(const float*)d_in[3], (const float*)d_in[7], (const float*)d_in[11],
                           (const float*)d_in[15]};
  const float* gcn_b[4] = {(const float*)d_in[4], (const float*)d_in[8], (const float*)d_in[12],
                           (const float*)d_in[16]};
  const float* bn_g[4] = {(const float*)d_in[5], (const float*)d_in[9], (const float*)d_in[13],
                          (const float*)d_in[17]};
  const float* bn_b[4] = {(const float*)d_in[6], (const float*)d_in[10], (const float*)d_in[14],
                          (const float*)d_in[18]};
  const float* gat_w0 = (const float*)d_in[19];
  const float* gat_as0 = (const float*)d_in[20];
  const float* gat_ad0 = (const float*)d_in[21];
  const float* gat_b0 = (const float*)d_in[22];
  const float* gat_w2 = (const float*)d_in[23];
  const float* gat_as2 = (const float*)d_in[24];
  const float* gat_ad2 = (const float*)d_in[25];
  const float* gat_b2 = (const float*)d_in[26];

  const int N = in_sizes[2];      // 100000
  const int E = in_sizes[1] / 2;  // 1600000

  char* wp = (char*)d_ws;
  auto alloc = [&](size_t bytes) -> void* {
    void* p = (void*)wp;
    wp += (bytes + 255) & ~(size_t)255;
    return p;
  };
  double* stats = (double*)alloc(256 * sizeof(double));
  float* coef = (float*)alloc(256 * sizeof(float));
  int* rowptr = (int*)alloc((size_t)(N + 1) * 4);
  int* cursor = (int*)alloc((size_t)N * 4);
  int* partial = (int*)alloc(256 * sizeof(int));
  int* csr = (int*)alloc((size_t)(N + E) * 4);
  float* dis = (float*)alloc((size_t)N * 4);
  h16* bufA = (h16*)alloc((size_t)N * 128 * 2);
  h16* bufB = (h16*)alloc((size_t)N * 128 * 2);
  h16* bufC = (h16*)alloc((size_t)N * 128 * 2);
  float* attS = (float*)alloc((size_t)N * 4 * 4);
  float* attD = (float*)alloc((size_t)N * 4 * 4);
  float* exbuf = (float*)alloc((size_t)(N + E) * 4 * 4);
  float* dinv = (float*)alloc((size_t)N * 4 * 4);
  int* bounds = (int*)alloc((size_t)(GRAPHS + 1) * 4);
  if ((size_t)(wp - (char*)d_ws) > ws_size) return;

  const int B = 256;
  auto cd = [](int a, int b) { return (a + b - 1) / b; };
  const int scan_blocks = cd(N, SCAN_CHUNK);  // 98 <= 256

  // --- CSR build ---
  init_counts_kernel<<<cd(N, B), B, 0, stream>>>(cursor, N);
  count_edges_kernel<<<cd(E, B), B, 0, stream>>>(ei, cursor, E);
  block_sum_kernel<<<scan_blocks, B, 0, stream>>>(cursor, partial, N);
  partial_scan_kernel<<<1, B, 0, stream>>>(partial, rowptr, scan_blocks, N);
  chunk_scan_kernel<<<scan_blocks, B, 0, stream>>>(cursor, partial, rowptr, N);
  finalize_csr_kernel<<<cd(N, B), B, 0, stream>>>(rowptr, dis, cursor, csr, N);
  {
    int nb = cd(N, XCDS);  // nodes per bucket
    fill_edges_kernel<<<XCDS * 512, B, 0, stream>>>(ei, cursor, csr, E, nb);
  }
  graph_bounds_kernel<<<1, 256, 0, stream>>>(batch, bounds, N);

  auto bn = [&](h16* buf, int D, const float* g, const float* b, bool act) {
    zero_f32_kernel<<<cd(512, B), B, 0, stream>>>((float*)stats, 512);
    if (D == 64) {
      bn_stats_kernel<64><<<256, 256, 0, stream>>>(buf, stats, N);
      bn_coef_kernel<64><<<1, 64, 0, stream>>>(stats, g, b, coef, N);
      int total2 = N * 32;
      if (act)
        bn_apply_kernel<64, true><<<cd(total2, B), B, 0, stream>>>(buf, coef, total2);
      else
        bn_apply_kernel<64, false><<<cd(total2, B), B, 0, stream>>>(buf, coef, total2);
    } else {
      bn_stats_kernel<128><<<256, 256, 0, stream>>>(buf, stats, N);
      bn_coef_kernel<128><<<1, 128, 0, stream>>>(stats, g, b, coef, N);
      int total2 = N * 64;
      if (act)
        bn_apply_kernel<128, true><<<cd(total2, B), B, 0, stream>>>(buf, coef, total2);
      else
        bn_apply_kernel<128, false><<<cd(total2, B), B, 0, stream>>>(buf, coef, total2);
    }
  };

  // ---- Layer 0: GCN 16->64 (aggregate at 16, then transform), BN ----
  gcn_agg16_kernel<<<cd(N * 64, B), B, 0, stream>>>(x_in, rowptr, csr, dis, bufB, N);
  gemm_tile_kernel<16, 64, 8><<<cd(N, 128), B, 0, stream>>>(bufB, gcn_w[0], gcn_b[0], bufC, N);
  bn(bufC, 64, bn_g[0], bn_b[0], false);
  // GAT0 (D=64, C=16) + residual + lrelu -> bufA
  gemm_tile_kernel<64, 64, 8><<<cd(N, 128), B, 0, stream>>>(bufC, gat_w0, nullptr, bufB, N);
  att_coef_kernel<16><<<cd(N * 4, B), B, 0, stream>>>(bufB, gat_as0, gat_ad0, attS, attD, N);
  edge_coef_kernel<<<cd(N * 64, B), B, 0, stream>>>(rowptr, csr, attS, attD, exbuf, dinv, N);
  gat_agg64_kernel<<<cd(N * 64, B), B, 0, stream>>>(bufB, rowptr, csr, exbuf, dinv, gat_b0, bufC,
                                                    bufA, N);

  // ---- Layer 1: GCN 64->128 (aggregate at 64, then transform), BN + lrelu -> bufC ----
  gcn_agg64_kernel<<<cd(N * 64, B), B, 0, stream>>>(bufA, rowptr, csr, dis, nullptr, bufB, N);
  gemm_tile_kernel<64, 128, 8><<<cd(N, 64), B, 0, stream>>>(bufB, gcn_w[1], gcn_b[1], bufC, N);
  bn(bufC, 128, bn_g[1], bn_b[1], true);

  // ---- Layer 2: GCN 128->128 (aggregate first), BN ----
  gcn_agg128_kernel<<<cd(N * 64, B), B, 0, stream>>>(bufC, rowptr, csr, dis, bufB, N);
  gemm_tile_kernel<128, 128, 8><<<cd(N, 64), B, 0, stream>>>(bufB, gcn_w[2], gcn_b[2], bufA, N);
  bn(bufA, 128, bn_g[2], bn_b[2], false);
  // GAT2 (D=128, C=32) + residual + lrelu -> bufC
  gemm_tile_kernel<128, 128, 8><<<cd(N, 64), B, 0, stream>>>(bufA, gat_w2, nullptr, bufB, N);
  att_coef_kernel<32><<<cd(N * 4, B), B, 0, stream>>>(bufB, gat_as2, gat_ad2, attS, attD, N);
  edge_coef_kernel<<<cd(N * 64, B), B, 0, stream>>>(rowptr, csr, attS, attD, exbuf, dinv, N);
  gat_agg128_kernel<<<cd(N * 64, B), B, 0, stream>>>(bufB, rowptr, csr, exbuf, dinv, gat_b2, bufA,
                                                     bufC, N);

  // ---- Layer 3: GCN 128->64 (transform first, aggregate at 64 with bias), BN ----
  gemm_tile_kernel<128, 64, 4><<<cd(N, 64), B, 0, stream>>>(bufC, gcn_w[3], nullptr, bufB, N);
  gcn_agg64_kernel<<<cd(N * 64, B), B, 0, stream>>>(bufB, rowptr, csr, dis, gcn_b[3], bufA, N);
  bn(bufA, 64, bn_g[3], bn_b[3], false);

  // ---- global mean pool ----
  pool_kernel<<<GRAPHS, 256, 0, stream>>>(bufA, bounds, (float*)d_out);
}